// Round 9
// baseline (676.262 us; speedup 1.0000x reference)
//
#include <hip/hip_runtime.h>
#include <hip/hip_bf16.h>

typedef __bf16 bf16;
typedef bf16 bf16x8 __attribute__((ext_vector_type(8)));
typedef bf16 bf16x4 __attribute__((ext_vector_type(4)));
typedef float f32x4 __attribute__((ext_vector_type(4)));
typedef float f32x16 __attribute__((ext_vector_type(16)));

#define AS1 __attribute__((address_space(1)))
#define AS3 __attribute__((address_space(3)))

static constexpr int SEQ = 2048;
static constexpr int NH  = 16;
static constexpr int DH  = 64;
static constexpr float SCLQ = 0.125f * 1.44269504088896340736f; // 1/sqrt(64)*log2(e)

__device__ __forceinline__ void gload16(const void* g, void* l) {
  __builtin_amdgcn_global_load_lds((const AS1 void*)g, (AS3 void*)l, 16, 0, 0);
}

__device__ __forceinline__ unsigned pk2(float a, float b) {
  union { bf16 h[2]; unsigned u; } z;
  z.h[0] = (bf16)a; z.h[1] = (bf16)b;
  return z.u;
}

// v_permlane32_swap_b32: a.upper32lanes <-> b.lower32lanes
__device__ __forceinline__ void plswap(unsigned &a, unsigned &b) {
  asm volatile("v_permlane32_swap_b32 %0, %1" : "+v"(a), "+v"(b));
}

#define MFMA32(d, a, b) d = __builtin_amdgcn_mfma_f32_32x32x16_bf16(a, b, d, 0, 0, 0)

// ---------- weight transpose + fp32->bf16 : Wt[n][k] = W[k][n] ----------
__global__ __launch_bounds__(256) void prep_w(
    const float* __restrict__ w0, const float* __restrict__ w1,
    const float* __restrict__ w2, const float* __restrict__ w3,
    const float* __restrict__ w4, const float* __restrict__ w5,
    bf16* __restrict__ dst)
{
  __shared__ float tile[64][65];
  int bid = blockIdx.x;
  int wi = bid >> 8;
  int tl = bid & 255;
  int tk = (tl >> 4) << 6;
  int tn = (tl & 15) << 6;
  const float* W = w0;
  if (wi == 1) W = w1; else if (wi == 2) W = w2; else if (wi == 3) W = w3;
  else if (wi == 4) W = w4; else if (wi == 5) W = w5;
  int t = threadIdx.x;
  #pragma unroll
  for (int rep = 0; rep < 16; ++rep) {
    int idx = rep * 256 + t;
    int i = idx >> 6, j = idx & 63;
    tile[i][j] = W[(size_t)(tk + i) * 1024 + tn + j];
  }
  __syncthreads();
  bf16* out = dst + (size_t)wi * 1024 * 1024;
  #pragma unroll
  for (int rep = 0; rep < 16; ++rep) {
    int idx = rep * 256 + t;
    int i = idx >> 6, j = idx & 63;
    out[(size_t)(tn + i) * 1024 + tk + j] = (bf16)tile[j][i];
  }
}

// ---------- LayerNorm: fp32 in -> bf16 out (one row per block) ----------
__global__ __launch_bounds__(256) void ln_k(
    const float* __restrict__ x, const float* __restrict__ g,
    const float* __restrict__ bb, bf16* __restrict__ out)
{
  int row = blockIdx.x;
  int t = threadIdx.x;
  float4 v = ((const float4*)(x + (size_t)row * 1024))[t];
  float s  = v.x + v.y + v.z + v.w;
  float s2 = v.x * v.x + v.y * v.y + v.z * v.z + v.w * v.w;
  #pragma unroll
  for (int m = 1; m < 64; m <<= 1) { s += __shfl_xor(s, m); s2 += __shfl_xor(s2, m); }
  __shared__ float red[8];
  int w = t >> 6;
  if ((t & 63) == 0) { red[w] = s; red[4 + w] = s2; }
  __syncthreads();
  s  = red[0] + red[1] + red[2] + red[3];
  s2 = red[4] + red[5] + red[6] + red[7];
  float mu  = s * (1.0f / 1024.0f);
  float var = s2 * (1.0f / 1024.0f) - mu * mu;
  float rst = rsqrtf(var + 1e-5f);
  float4 gv = ((const float4*)g)[t];
  float4 bv = ((const float4*)bb)[t];
  bf16x4 o;
  o[0] = (bf16)((v.x - mu) * rst * gv.x + bv.x);
  o[1] = (bf16)((v.y - mu) * rst * gv.y + bv.y);
  o[2] = (bf16)((v.z - mu) * rst * gv.z + bv.z);
  o[3] = (bf16)((v.w - mu) * rst * gv.w + bv.w);
  *(bf16x4*)(out + (size_t)row * 1024 + t * 4) = o;
}

// ---------- GEMM: C[M=8192][N=NT*128] = A[M][1024] * Bt[N][1024]^T ----------
// m97 structure (round-3 verified): 128x128 tile, BK=64, 4 waves.
template<int EPI, int NT>
__global__ __launch_bounds__(256) void gemm_k(
    const bf16* __restrict__ A, const bf16* __restrict__ Bt,
    const float* __restrict__ bias, const float* __restrict__ res,
    float* __restrict__ outf, bf16* __restrict__ outb)
{
  __shared__ bf16 lA[128 * 64];
  __shared__ bf16 lB[128 * 64];
  int t = threadIdx.x;
  int wg = blockIdx.x;
  int swz = (wg & 7) * (NT * 8) + (wg >> 3);   // XCD-bijective swizzle
  int mt = swz / NT, nt = swz % NT;
  int lane = t & 63, w = t >> 6;
  int l16 = lane & 15, lh = lane >> 4;
  int wr = w >> 1, wc = w & 1;

  f32x4 acc[4][4] = {};
  const size_t mbase = (size_t)mt * 128;
  const size_t nbase = (size_t)nt * 128;
  int u = t & 7;

  for (int ks = 0; ks < 16; ++ks) {
    int k0 = ks * 64;
    #pragma unroll
    for (int i = 0; i < 4; ++i) {
      int row = i * 32 + (t >> 3);
      int up = u ^ (row & 7);
      gload16(A  + (mbase + row) * 1024 + k0 + up * 8, lA + i * 2048 + w * 512);
      gload16(Bt + (nbase + row) * 1024 + k0 + up * 8, lB + i * 2048 + w * 512);
    }
    __syncthreads();
    #pragma unroll
    for (int kc = 0; kc < 2; ++kc) {
      bf16x8 af[4], bfr[4];
      #pragma unroll
      for (int mi = 0; mi < 4; ++mi) {
        int row = wr * 64 + mi * 16 + l16;
        af[mi] = *(const bf16x8*)(lA + row * 64 + (((kc * 4 + lh) ^ (row & 7)) * 8));
      }
      #pragma unroll
      for (int ni = 0; ni < 4; ++ni) {
        int row = wc * 64 + ni * 16 + l16;
        bfr[ni] = *(const bf16x8*)(lB + row * 64 + (((kc * 4 + lh) ^ (row & 7)) * 8));
      }
      #pragma unroll
      for (int mi = 0; mi < 4; ++mi)
        #pragma unroll
        for (int ni = 0; ni < 4; ++ni)
          acc[mi][ni] = __builtin_amdgcn_mfma_f32_16x16x32_bf16(af[mi], bfr[ni], acc[mi][ni], 0, 0, 0);
    }
    __syncthreads();
  }

  int mrow0 = mt * 128 + wr * 64;
  int ncol0 = nt * 128 + wc * 64;
  #pragma unroll
  for (int mi = 0; mi < 4; ++mi) {
    #pragma unroll
    for (int ni = 0; ni < 4; ++ni) {
      if constexpr (EPI == 0) {
        int gcol = ncol0 + ni * 16 + l16;
        int which = gcol >> 10;                  // 0=q 1=k 2=v
        int col = gcol & 1023;
        int h = col >> 6, dh = col & 63;
        bf16* dst = outb + (size_t)which * (size_t)(4 * NH * SEQ * DH);
        if (which == 2) {
          int s0 = mrow0 + mi * 16 + lh * 4;
          int b = s0 >> 11, s = s0 & 2047;
          bf16x4 pkv;
          #pragma unroll
          for (int r = 0; r < 4; ++r) pkv[r] = (bf16)acc[mi][ni][r];
          *(bf16x4*)(dst + (((size_t)((b * NH + h) * DH + dh)) << 11) + s) = pkv;
        } else {
          #pragma unroll
          for (int r = 0; r < 4; ++r) {
            int grow = mrow0 + mi * 16 + lh * 4 + r;
            int b = grow >> 11, s = grow & 2047;
            float v = acc[mi][ni][r];
            if (which == 0) v *= SCLQ;           // fold softmax scale into q
            dst[(((size_t)((b * NH + h) * SEQ + s)) << 6) + dh] = (bf16)v;
          }
        }
      } else {
        #pragma unroll
        for (int r = 0; r < 4; ++r) {
          int grow = mrow0 + mi * 16 + lh * 4 + r;
          int gcol = ncol0 + ni * 16 + l16;
          float v = acc[mi][ni][r];
          if constexpr (EPI == 2) {
            size_t idx = (size_t)grow * 1024 + gcol;
            outf[idx] = v + bias[gcol] + res[idx];
          } else {
            size_t idx = (size_t)grow * 1024 + gcol;
            float z = v + bias[gcol];
            outb[idx] = (bf16)(z > 0.f ? z : 0.f);
          }
        }
      }
    }
  }
}

// ---------- flash attention, K-split x2, swapped-QK 32x32, 2 q-tiles/wave ----------
// Block = (bh, qt, half): processes 16 of 32 K/V tiles. Grid 1024 -> 4 blocks/CU
// (16 waves/CU). Static m=0 softmax => partials exactly additive:
// half 0 writes f32 O-sums to pA (d_out scratch), half 1 writes bf16 to pB;
// per-row lsums to lsA/lsB. attn_combine normalizes.
__global__ __launch_bounds__(256, 4) void attn_k(
    const bf16* __restrict__ q, const bf16* __restrict__ kk,
    const bf16* __restrict__ vt,
    float* __restrict__ pA, bf16* __restrict__ pB,
    float* __restrict__ lsA, float* __restrict__ lsB)
{
  __shared__ bf16 lK[2][4096];   // [key 0..63][dh 0..63], unit-swizzled
  __shared__ bf16 lV[2][4096];   // [dh 0..63][key 0..63], unit-swizzled

  int t = threadIdx.x;
  int lane = t & 63, w = t >> 6;
  int l31 = lane & 31, hi = lane >> 5;
  int bid = blockIdx.x;
  int swz = (bid & 7) * 128 + (bid >> 3);  // XCD-bijective over 1024
  int half = swz & 1;                       // halves of same (bh,qt) same XCD
  int rest = swz >> 1;                      // 0..511
  int bh = rest >> 3, qt = rest & 7;
  int q0 = qt * 256 + w * 64;
  size_t bhS = (size_t)bh * SEQ;

  // Q fragments (B-operand): lane holds q = base+l31, dh = ks*16 + hi*8 + j
  const bf16* qrow0 = q + (bhS + q0 + l31) * 64 + hi * 8;
  const bf16* qrow1 = qrow0 + 32 * 64;
  bf16x8 aq0[4], aq1[4];
  #pragma unroll
  for (int ks = 0; ks < 4; ++ks) {
    aq0[ks] = *(const bf16x8*)(qrow0 + ks * 16);
    aq1[ks] = *(const bf16x8*)(qrow1 + ks * 16);
  }

  // staging source addresses (per-lane, pre-swizzled on the 16B unit)
  int srow = t >> 3;
  int u8 = (t & 7) ^ (srow & 7);
  const bf16* kSrc = kk + (bhS + half * 1024 + srow) * 64 + u8 * 8;
  const bf16* vSrc = vt + ((size_t)bh * 64 + srow) * SEQ + half * 1024 + u8 * 8;

  f32x16 oa00 = {}, oa01 = {}, oa10 = {}, oa11 = {};
  float lsum0 = 0.f, lsum1 = 0.f;

  // prologue: stage tile 0 into buffer 0
  gload16(kSrc,            &lK[0][w * 512]);
  gload16(kSrc + 2048,     &lK[0][2048 + w * 512]);
  gload16(vSrc,            &lV[0][w * 512]);
  gload16(vSrc + 32 * SEQ, &lV[0][2048 + w * 512]);
  __syncthreads();

  #pragma unroll 2
  for (int kt = 0; kt < 16; ++kt) {
    const int cur = kt & 1;
    // prefetch next tile into the other buffer (issue before compute)
    if (kt < 15) {
      const bf16* ks2 = kSrc + (size_t)(kt + 1) * 4096;
      const bf16* vs2 = vSrc + (kt + 1) * 64;
      gload16(ks2,            &lK[cur ^ 1][w * 512]);
      gload16(ks2 + 2048,     &lK[cur ^ 1][2048 + w * 512]);
      gload16(vs2,            &lV[cur ^ 1][w * 512]);
      gload16(vs2 + 32 * SEQ, &lV[cur ^ 1][2048 + w * 512]);
    }

    const bf16* bK = &lK[cur][0];
    const bf16* bV = &lV[cur][0];

    // QK^T (swapped): 4 independent accumulator chains
    f32x16 sA0 = {}, sB0 = {}, sA1 = {}, sB1 = {};
    __builtin_amdgcn_s_setprio(1);
    #pragma unroll
    for (int ks = 0; ks < 4; ++ks) {
      int u = ((2 * ks + hi) ^ (l31 & 7)) * 8;
      bf16x8 k0 = *(const bf16x8*)(bK + l31 * 64 + u);
      bf16x8 k1 = *(const bf16x8*)(bK + (32 + l31) * 64 + u);
      MFMA32(sA0, k0, aq0[ks]);
      MFMA32(sA1, k0, aq1[ks]);
      MFMA32(sB0, k1, aq0[ks]);
      MFMA32(sB1, k1, aq1[ks]);
    }
    __builtin_amdgcn_s_setprio(0);

    // softmax (static m=0) + pack/swap into PV A-fragments, per q-tile
    unsigned cv0[4][4], cv1[4][4];
    {
      float p[32];
      #pragma unroll
      for (int i = 0; i < 16; ++i) {
        p[i]      = __builtin_amdgcn_exp2f(sA0[i]);
        p[16 + i] = __builtin_amdgcn_exp2f(sB0[i]);
      }
      float t8[8];
      #pragma unroll
      for (int i = 0; i < 8; ++i)
        t8[i] = (p[4 * i] + p[4 * i + 1]) + (p[4 * i + 2] + p[4 * i + 3]);
      lsum0 += ((t8[0] + t8[1]) + (t8[2] + t8[3])) + ((t8[4] + t8[5]) + (t8[6] + t8[7]));
      #pragma unroll
      for (int ks = 0; ks < 4; ++ks) {
        int g = 8 * ks;
        unsigned X0 = pk2(p[g],     p[g + 1]), X1 = pk2(p[g + 2], p[g + 3]);
        unsigned Y0 = pk2(p[g + 4], p[g + 5]), Y1 = pk2(p[g + 6], p[g + 7]);
        plswap(X0, Y0);
        plswap(X1, Y1);
        cv0[ks][0] = X0; cv0[ks][1] = X1; cv0[ks][2] = Y0; cv0[ks][3] = Y1;
      }
    }
    {
      float p[32];
      #pragma unroll
      for (int i = 0; i < 16; ++i) {
        p[i]      = __builtin_amdgcn_exp2f(sA1[i]);
        p[16 + i] = __builtin_amdgcn_exp2f(sB1[i]);
      }
      float t8[8];
      #pragma unroll
      for (int i = 0; i < 8; ++i)
        t8[i] = (p[4 * i] + p[4 * i + 1]) + (p[4 * i + 2] + p[4 * i + 3]);
      lsum1 += ((t8[0] + t8[1]) + (t8[2] + t8[3])) + ((t8[4] + t8[5]) + (t8[6] + t8[7]));
      #pragma unroll
      for (int ks = 0; ks < 4; ++ks) {
        int g = 8 * ks;
        unsigned X0 = pk2(p[g],     p[g + 1]), X1 = pk2(p[g + 2], p[g + 3]);
        unsigned Y0 = pk2(p[g + 4], p[g + 5]), Y1 = pk2(p[g + 6], p[g + 7]);
        plswap(X0, Y0);
        plswap(X1, Y1);
        cv1[ks][0] = X0; cv1[ks][1] = X1; cv1[ks][2] = Y0; cv1[ks][3] = Y1;
      }
    }

    // PV: 4 independent chains, shared V fragments
    __builtin_amdgcn_s_setprio(1);
    #pragma unroll
    for (int ks = 0; ks < 4; ++ks) {
      int u = ((2 * ks + hi) ^ (l31 & 7)) * 8;
      bf16x8 v0 = *(const bf16x8*)(bV + l31 * 64 + u);
      bf16x8 v1 = *(const bf16x8*)(bV + (32 + l31) * 64 + u);
      union { unsigned u4[4]; bf16x8 v; } a0, a1;
      a0.u4[0] = cv0[ks][0]; a0.u4[1] = cv0[ks][1]; a0.u4[2] = cv0[ks][2]; a0.u4[3] = cv0[ks][3];
      a1.u4[0] = cv1[ks][0]; a1.u4[1] = cv1[ks][1]; a1.u4[2] = cv1[ks][2]; a1.u4[3] = cv1[ks][3];
      MFMA32(oa00, a0.v, v0);
      MFMA32(oa01, a0.v, v1);
      MFMA32(oa10, a1.v, v0);
      MFMA32(oa11, a1.v, v1);
    }
    __builtin_amdgcn_s_setprio(0);

    __syncthreads();  // drains vmcnt (prefetch landed) + lgkm; flips buffer
  }

  // epilogue: combine lane-halves of l; store un-normalized partials + lsums
  lsum0 += __shfl_xor(lsum0, 32);
  lsum1 += __shfl_xor(lsum1, 32);
  float* ls = half ? lsB : lsA;
  if (hi == 0) {
    ls[bh * 2048 + q0 + l31]      = lsum0;   // rows q0..q0+31
    ls[bh * 2048 + q0 + 32 + l31] = lsum1;   // rows q0+32..q0+63
  }
  int bb = bh >> 4, hh = bh & 15;
  size_t obase = ((size_t)bb * SEQ + q0) * 1024 + (size_t)hh * 64;
  #pragma unroll
  for (int r = 0; r < 16; ++r) {
    int qrw = (r & 3) + 8 * (r >> 2) + 4 * hi;    // C/D row within 32
    size_t b0 = obase + (size_t)qrw * 1024;
    size_t b1 = obase + (size_t)(32 + qrw) * 1024;
    if (half == 0) {
      pA[b0 + l31]      = oa00[r];
      pA[b0 + 32 + l31] = oa01[r];
      pA[b1 + l31]      = oa10[r];
      pA[b1 + 32 + l31] = oa11[r];
    } else {
      pB[b0 + l31]      = (bf16)oa00[r];
      pB[b0 + 32 + l31] = (bf16)oa01[r];
      pB[b1 + l31]      = (bf16)oa10[r];
      pB[b1 + 32 + l31] = (bf16)oa11[r];
    }
  }
}

// ---------- combine: ob = (pA + pB) / (lsA + lsB), in-place over pB ----------
__global__ __launch_bounds__(256) void attn_combine(
    const float* __restrict__ pA, const bf16* __restrict__ pBr,
    const float* __restrict__ lsA, const float* __restrict__ lsB,
    bf16* __restrict__ ob)
{
  size_t c = (size_t)blockIdx.x * 256 + threadIdx.x;  // 4-elem chunk id
  size_t i = c * 4;
  int b = (int)(i >> 21);
  int s = (int)((i >> 10) & 2047);
  int h = (int)((i >> 6) & 15);
  int li = (b * 16 + h) * 2048 + s;
  float inv = 1.0f / (lsA[li] + lsB[li]);
  float4 a = *(const float4*)(pA + i);
  bf16x4 bq = *(const bf16x4*)(pBr + i);
  bf16x4 o;
  o[0] = (bf16)((a.x + (float)bq[0]) * inv);
  o[1] = (bf16)((a.y + (float)bq[1]) * inv);
  o[2] = (bf16)((a.z + (float)bq[2]) * inv);
  o[3] = (bf16)((a.w + (float)bq[3]) * inv);
  *(bf16x4*)(ob + i) = o;   // same address as pBr[i]: per-thread in-place, safe
}

extern "C" void kernel_launch(void* const* d_in, const int* in_sizes, int n_in,
                              void* d_out, int out_size, void* d_ws, size_t ws_size,
                              hipStream_t stream) {
  const float* x   = (const float*)d_in[0];
  const float* wq  = (const float*)d_in[1];
  const float* wk  = (const float*)d_in[2];
  const float* wv  = (const float*)d_in[3];
  const float* wo  = (const float*)d_in[4];
  const float* bo  = (const float*)d_in[5];
  const float* gx  = (const float*)d_in[6];
  const float* bx  = (const float*)d_in[7];
  const float* gf  = (const float*)d_in[8];
  const float* bfp = (const float*)d_in[9];
  const float* w1  = (const float*)d_in[10];
  const float* b1  = (const float*)d_in[11];
  const float* w2  = (const float*)d_in[12];
  const float* b2  = (const float*)d_in[13];

  char* ws = (char*)d_ws;
  const size_t MB = 1024 * 1024;
  bf16*  wT  = (bf16*)ws;                // 6 x 2MB bf16 transposed weights
  bf16*  xs  = (bf16*)(ws + 12 * MB);    // LN1 out (dead after QKV)
  bf16*  qb  = (bf16*)(ws + 28 * MB);    // q,k,vt contiguous (dead after attn)
  bf16*  kb  = (bf16*)(ws + 44 * MB);
  bf16*  vtb = (bf16*)(ws + 60 * MB);
  // attn scratch (regions dead during attention):
  float* pA  = (float*)d_out;            // f32 partial (half 0), 32 MiB
  bf16*  pB  = (bf16*)(ws + 12 * MB);    // bf16 partial (half 1) over xs, 16 MiB
  float* lsA = (float*)ws;               // 0.5 MiB over dead wq^T
  float* lsB = (float*)(ws + 524288);    // 0.5 MiB
  bf16*  ob  = (bf16*)(ws + 12 * MB);    // combined attn out (in-place over pB)
  float* xt  = (float*)(ws + 28 * MB);   // residual fp32, reuses q+k (32 MiB)
  bf16*  hb  = (bf16*)(ws + 60 * MB);    // LN2 out, reuses vt
  bf16*  a1  = (bf16*)(ws + 12 * MB);    // FFN mid, reuses ob
  float* out = (float*)d_out;

  prep_w<<<1536, 256, 0, stream>>>(wq, wk, wv, wo, w1, w2, wT);
  ln_k<<<8192, 256, 0, stream>>>(x, gx, bx, xs);
  gemm_k<0, 24><<<1536, 256, 0, stream>>>(xs, wT, nullptr, nullptr, nullptr, qb);
  attn_k<<<1024, 256, 0, stream>>>(qb, kb, vtb, pA, pB, lsA, lsB);
  attn_combine<<<8192, 256, 0, stream>>>(pA, pB, lsA, lsB, ob);
  gemm_k<2, 8><<<512, 256, 0, stream>>>(ob, wT + (size_t)3 * MB, bo, x, xt, nullptr);
  ln_k<<<8192, 256, 0, stream>>>(xt, gf, bfp, hb);
  gemm_k<3, 8><<<512, 256, 0, stream>>>(hb, wT + (size_t)4 * MB, b1, nullptr, nullptr, a1);
  gemm_k<2, 8><<<512, 256, 0, stream>>>(a1, wT + (size_t)5 * MB, b2, xt, out, nullptr);
}

// Round 10
// 284.637 us; speedup vs baseline: 2.3759x; 2.3759x over previous
//
#include <hip/hip_runtime.h>
#include <hip/hip_bf16.h>

typedef __bf16 bf16;
typedef bf16 bf16x8 __attribute__((ext_vector_type(8)));
typedef bf16 bf16x4 __attribute__((ext_vector_type(4)));
typedef float f32x4 __attribute__((ext_vector_type(4)));
typedef float f32x16 __attribute__((ext_vector_type(16)));

#define AS1 __attribute__((address_space(1)))
#define AS3 __attribute__((address_space(3)))

static constexpr int SEQ = 2048;
static constexpr int NH  = 16;
static constexpr int DH  = 64;
static constexpr float SCLQ = 0.125f * 1.44269504088896340736f; // 1/sqrt(64)*log2(e)

__device__ __forceinline__ void gload16(const void* g, void* l) {
  __builtin_amdgcn_global_load_lds((const AS1 void*)g, (AS3 void*)l, 16, 0, 0);
}

__device__ __forceinline__ unsigned pk2(float a, float b) {
  union { bf16 h[2]; unsigned u; } z;
  z.h[0] = (bf16)a; z.h[1] = (bf16)b;
  return z.u;
}

// v_permlane32_swap_b32: a.upper32lanes <-> b.lower32lanes
__device__ __forceinline__ void plswap(unsigned &a, unsigned &b) {
  asm volatile("v_permlane32_swap_b32 %0, %1" : "+v"(a), "+v"(b));
}

#define MFMA32(d, a, b) d = __builtin_amdgcn_mfma_f32_32x32x16_bf16(a, b, d, 0, 0, 0)

// ---------- weight transpose + fp32->bf16 : Wt[n][k] = W[k][n] ----------
__global__ __launch_bounds__(256) void prep_w(
    const float* __restrict__ w0, const float* __restrict__ w1,
    const float* __restrict__ w2, const float* __restrict__ w3,
    const float* __restrict__ w4, const float* __restrict__ w5,
    bf16* __restrict__ dst)
{
  __shared__ float tile[64][65];
  int bid = blockIdx.x;
  int wi = bid >> 8;
  int tl = bid & 255;
  int tk = (tl >> 4) << 6;
  int tn = (tl & 15) << 6;
  const float* W = w0;
  if (wi == 1) W = w1; else if (wi == 2) W = w2; else if (wi == 3) W = w3;
  else if (wi == 4) W = w4; else if (wi == 5) W = w5;
  int t = threadIdx.x;
  #pragma unroll
  for (int rep = 0; rep < 16; ++rep) {
    int idx = rep * 256 + t;
    int i = idx >> 6, j = idx & 63;
    tile[i][j] = W[(size_t)(tk + i) * 1024 + tn + j];
  }
  __syncthreads();
  bf16* out = dst + (size_t)wi * 1024 * 1024;
  #pragma unroll
  for (int rep = 0; rep < 16; ++rep) {
    int idx = rep * 256 + t;
    int i = idx >> 6, j = idx & 63;
    out[(size_t)(tn + i) * 1024 + tk + j] = (bf16)tile[j][i];
  }
}

// ---------- LayerNorm: fp32 in -> bf16 out (one row per block) ----------
__global__ __launch_bounds__(256) void ln_k(
    const float* __restrict__ x, const float* __restrict__ g,
    const float* __restrict__ bb, bf16* __restrict__ out)
{
  int row = blockIdx.x;
  int t = threadIdx.x;
  float4 v = ((const float4*)(x + (size_t)row * 1024))[t];
  float s  = v.x + v.y + v.z + v.w;
  float s2 = v.x * v.x + v.y * v.y + v.z * v.z + v.w * v.w;
  #pragma unroll
  for (int m = 1; m < 64; m <<= 1) { s += __shfl_xor(s, m); s2 += __shfl_xor(s2, m); }
  __shared__ float red[8];
  int w = t >> 6;
  if ((t & 63) == 0) { red[w] = s; red[4 + w] = s2; }
  __syncthreads();
  s  = red[0] + red[1] + red[2] + red[3];
  s2 = red[4] + red[5] + red[6] + red[7];
  float mu  = s * (1.0f / 1024.0f);
  float var = s2 * (1.0f / 1024.0f) - mu * mu;
  float rst = rsqrtf(var + 1e-5f);
  float4 gv = ((const float4*)g)[t];
  float4 bv = ((const float4*)bb)[t];
  bf16x4 o;
  o[0] = (bf16)((v.x - mu) * rst * gv.x + bv.x);
  o[1] = (bf16)((v.y - mu) * rst * gv.y + bv.y);
  o[2] = (bf16)((v.z - mu) * rst * gv.z + bv.z);
  o[3] = (bf16)((v.w - mu) * rst * gv.w + bv.w);
  *(bf16x4*)(out + (size_t)row * 1024 + t * 4) = o;
}

// ---------- GEMM: C[M=8192][N=NT*128] = A[M][1024] * Bt[N][1024]^T ----------
// m97 structure (round-3 verified): 128x128 tile, BK=64, 4 waves.
template<int EPI, int NT>
__global__ __launch_bounds__(256) void gemm_k(
    const bf16* __restrict__ A, const bf16* __restrict__ Bt,
    const float* __restrict__ bias, const float* __restrict__ res,
    float* __restrict__ outf, bf16* __restrict__ outb)
{
  __shared__ bf16 lA[128 * 64];
  __shared__ bf16 lB[128 * 64];
  int t = threadIdx.x;
  int wg = blockIdx.x;
  int swz = (wg & 7) * (NT * 8) + (wg >> 3);   // XCD-bijective swizzle
  int mt = swz / NT, nt = swz % NT;
  int lane = t & 63, w = t >> 6;
  int l16 = lane & 15, lh = lane >> 4;
  int wr = w >> 1, wc = w & 1;

  f32x4 acc[4][4] = {};
  const size_t mbase = (size_t)mt * 128;
  const size_t nbase = (size_t)nt * 128;
  int u = t & 7;

  for (int ks = 0; ks < 16; ++ks) {
    int k0 = ks * 64;
    #pragma unroll
    for (int i = 0; i < 4; ++i) {
      int row = i * 32 + (t >> 3);
      int up = u ^ (row & 7);
      gload16(A  + (mbase + row) * 1024 + k0 + up * 8, lA + i * 2048 + w * 512);
      gload16(Bt + (nbase + row) * 1024 + k0 + up * 8, lB + i * 2048 + w * 512);
    }
    __syncthreads();
    #pragma unroll
    for (int kc = 0; kc < 2; ++kc) {
      bf16x8 af[4], bfr[4];
      #pragma unroll
      for (int mi = 0; mi < 4; ++mi) {
        int row = wr * 64 + mi * 16 + l16;
        af[mi] = *(const bf16x8*)(lA + row * 64 + (((kc * 4 + lh) ^ (row & 7)) * 8));
      }
      #pragma unroll
      for (int ni = 0; ni < 4; ++ni) {
        int row = wc * 64 + ni * 16 + l16;
        bfr[ni] = *(const bf16x8*)(lB + row * 64 + (((kc * 4 + lh) ^ (row & 7)) * 8));
      }
      #pragma unroll
      for (int mi = 0; mi < 4; ++mi)
        #pragma unroll
        for (int ni = 0; ni < 4; ++ni)
          acc[mi][ni] = __builtin_amdgcn_mfma_f32_16x16x32_bf16(af[mi], bfr[ni], acc[mi][ni], 0, 0, 0);
    }
    __syncthreads();
  }

  int mrow0 = mt * 128 + wr * 64;
  int ncol0 = nt * 128 + wc * 64;
  #pragma unroll
  for (int mi = 0; mi < 4; ++mi) {
    #pragma unroll
    for (int ni = 0; ni < 4; ++ni) {
      if constexpr (EPI == 0) {
        int gcol = ncol0 + ni * 16 + l16;
        int which = gcol >> 10;                  // 0=q 1=k 2=v
        int col = gcol & 1023;
        int h = col >> 6, dh = col & 63;
        bf16* dst = outb + (size_t)which * (size_t)(4 * NH * SEQ * DH);
        if (which == 2) {
          int s0 = mrow0 + mi * 16 + lh * 4;
          int b = s0 >> 11, s = s0 & 2047;
          bf16x4 pkv;
          #pragma unroll
          for (int r = 0; r < 4; ++r) pkv[r] = (bf16)acc[mi][ni][r];
          *(bf16x4*)(dst + (((size_t)((b * NH + h) * DH + dh)) << 11) + s) = pkv;
        } else {
          #pragma unroll
          for (int r = 0; r < 4; ++r) {
            int grow = mrow0 + mi * 16 + lh * 4 + r;
            int b = grow >> 11, s = grow & 2047;
            float v = acc[mi][ni][r];
            if (which == 0) v *= SCLQ;           // fold softmax scale into q
            dst[(((size_t)((b * NH + h) * SEQ + s)) << 6) + dh] = (bf16)v;
          }
        }
      } else {
        #pragma unroll
        for (int r = 0; r < 4; ++r) {
          int grow = mrow0 + mi * 16 + lh * 4 + r;
          int gcol = ncol0 + ni * 16 + l16;
          float v = acc[mi][ni][r];
          if constexpr (EPI == 2) {
            size_t idx = (size_t)grow * 1024 + gcol;
            outf[idx] = v + bias[gcol] + res[idx];
          } else {
            size_t idx = (size_t)grow * 1024 + gcol;
            float z = v + bias[gcol];
            outb[idx] = (bf16)(z > 0.f ? z : 0.f);
          }
        }
      }
    }
  }
}

// ---------- flash attention, K-split x2, swapped-QK 32x32, 2 q-tiles/wave ----------
// Block = (bh, qt, half): 16 of 32 K/V tiles. Grid 1024; VGPR ~124 (<=128) lets
// HW host 4 blocks/CU = 16 waves/CU at runtime. launch_bounds min kept at 2 —
// (256,4) capped VGPR to 64 and spilled catastrophically (round 9).
// Static m=0 softmax => partials exactly additive; combine normalizes.
__global__ __launch_bounds__(256, 2) void attn_k(
    const bf16* __restrict__ q, const bf16* __restrict__ kk,
    const bf16* __restrict__ vt,
    float* __restrict__ pA, bf16* __restrict__ pB,
    float* __restrict__ lsA, float* __restrict__ lsB)
{
  __shared__ bf16 lK[2][4096];   // [key 0..63][dh 0..63], unit-swizzled
  __shared__ bf16 lV[2][4096];   // [dh 0..63][key 0..63], unit-swizzled

  int t = threadIdx.x;
  int lane = t & 63, w = t >> 6;
  int l31 = lane & 31, hi = lane >> 5;
  int bid = blockIdx.x;
  int swz = (bid & 7) * 128 + (bid >> 3);  // XCD-bijective over 1024
  int half = swz & 1;                       // halves of same (bh,qt) same XCD
  int rest = swz >> 1;                      // 0..511
  int bh = rest >> 3, qt = rest & 7;
  int q0 = qt * 256 + w * 64;
  size_t bhS = (size_t)bh * SEQ;

  // Q fragments (B-operand): lane holds q = base+l31, dh = ks*16 + hi*8 + j
  const bf16* qrow0 = q + (bhS + q0 + l31) * 64 + hi * 8;
  const bf16* qrow1 = qrow0 + 32 * 64;
  bf16x8 aq0[4], aq1[4];
  #pragma unroll
  for (int ks = 0; ks < 4; ++ks) {
    aq0[ks] = *(const bf16x8*)(qrow0 + ks * 16);
    aq1[ks] = *(const bf16x8*)(qrow1 + ks * 16);
  }

  // staging source addresses (per-lane, pre-swizzled on the 16B unit)
  int srow = t >> 3;
  int u8 = (t & 7) ^ (srow & 7);
  const bf16* kSrc = kk + (bhS + half * 1024 + srow) * 64 + u8 * 8;
  const bf16* vSrc = vt + ((size_t)bh * 64 + srow) * SEQ + half * 1024 + u8 * 8;

  f32x16 oa00 = {}, oa01 = {}, oa10 = {}, oa11 = {};
  float lsum0 = 0.f, lsum1 = 0.f;

  // prologue: stage tile 0 into buffer 0
  gload16(kSrc,            &lK[0][w * 512]);
  gload16(kSrc + 2048,     &lK[0][2048 + w * 512]);
  gload16(vSrc,            &lV[0][w * 512]);
  gload16(vSrc + 32 * SEQ, &lV[0][2048 + w * 512]);
  __syncthreads();

  #pragma unroll 2
  for (int kt = 0; kt < 16; ++kt) {
    const int cur = kt & 1;
    // prefetch next tile into the other buffer (issue before compute)
    if (kt < 15) {
      const bf16* ks2 = kSrc + (size_t)(kt + 1) * 4096;
      const bf16* vs2 = vSrc + (kt + 1) * 64;
      gload16(ks2,            &lK[cur ^ 1][w * 512]);
      gload16(ks2 + 2048,     &lK[cur ^ 1][2048 + w * 512]);
      gload16(vs2,            &lV[cur ^ 1][w * 512]);
      gload16(vs2 + 32 * SEQ, &lV[cur ^ 1][2048 + w * 512]);
    }

    const bf16* bK = &lK[cur][0];
    const bf16* bV = &lV[cur][0];

    // QK^T (swapped): 4 independent accumulator chains
    f32x16 sA0 = {}, sB0 = {}, sA1 = {}, sB1 = {};
    __builtin_amdgcn_s_setprio(1);
    #pragma unroll
    for (int ks = 0; ks < 4; ++ks) {
      int u = ((2 * ks + hi) ^ (l31 & 7)) * 8;
      bf16x8 k0 = *(const bf16x8*)(bK + l31 * 64 + u);
      bf16x8 k1 = *(const bf16x8*)(bK + (32 + l31) * 64 + u);
      MFMA32(sA0, k0, aq0[ks]);
      MFMA32(sA1, k0, aq1[ks]);
      MFMA32(sB0, k1, aq0[ks]);
      MFMA32(sB1, k1, aq1[ks]);
    }
    __builtin_amdgcn_s_setprio(0);

    // softmax (static m=0) + pack/swap into PV A-fragments, per q-tile
    unsigned cv0[4][4], cv1[4][4];
    {
      float p[32];
      #pragma unroll
      for (int i = 0; i < 16; ++i) {
        p[i]      = __builtin_amdgcn_exp2f(sA0[i]);
        p[16 + i] = __builtin_amdgcn_exp2f(sB0[i]);
      }
      float t8[8];
      #pragma unroll
      for (int i = 0; i < 8; ++i)
        t8[i] = (p[4 * i] + p[4 * i + 1]) + (p[4 * i + 2] + p[4 * i + 3]);
      lsum0 += ((t8[0] + t8[1]) + (t8[2] + t8[3])) + ((t8[4] + t8[5]) + (t8[6] + t8[7]));
      #pragma unroll
      for (int ks = 0; ks < 4; ++ks) {
        int g = 8 * ks;
        unsigned X0 = pk2(p[g],     p[g + 1]), X1 = pk2(p[g + 2], p[g + 3]);
        unsigned Y0 = pk2(p[g + 4], p[g + 5]), Y1 = pk2(p[g + 6], p[g + 7]);
        plswap(X0, Y0);
        plswap(X1, Y1);
        cv0[ks][0] = X0; cv0[ks][1] = X1; cv0[ks][2] = Y0; cv0[ks][3] = Y1;
      }
    }
    {
      float p[32];
      #pragma unroll
      for (int i = 0; i < 16; ++i) {
        p[i]      = __builtin_amdgcn_exp2f(sA1[i]);
        p[16 + i] = __builtin_amdgcn_exp2f(sB1[i]);
      }
      float t8[8];
      #pragma unroll
      for (int i = 0; i < 8; ++i)
        t8[i] = (p[4 * i] + p[4 * i + 1]) + (p[4 * i + 2] + p[4 * i + 3]);
      lsum1 += ((t8[0] + t8[1]) + (t8[2] + t8[3])) + ((t8[4] + t8[5]) + (t8[6] + t8[7]));
      #pragma unroll
      for (int ks = 0; ks < 4; ++ks) {
        int g = 8 * ks;
        unsigned X0 = pk2(p[g],     p[g + 1]), X1 = pk2(p[g + 2], p[g + 3]);
        unsigned Y0 = pk2(p[g + 4], p[g + 5]), Y1 = pk2(p[g + 6], p[g + 7]);
        plswap(X0, Y0);
        plswap(X1, Y1);
        cv1[ks][0] = X0; cv1[ks][1] = X1; cv1[ks][2] = Y0; cv1[ks][3] = Y1;
      }
    }

    // PV: 4 independent chains, shared V fragments
    __builtin_amdgcn_s_setprio(1);
    #pragma unroll
    for (int ks = 0; ks < 4; ++ks) {
      int u = ((2 * ks + hi) ^ (l31 & 7)) * 8;
      bf16x8 v0 = *(const bf16x8*)(bV + l31 * 64 + u);
      bf16x8 v1 = *(const bf16x8*)(bV + (32 + l31) * 64 + u);
      union { unsigned u4[4]; bf16x8 v; } a0, a1;
      a0.u4[0] = cv0[ks][0]; a0.u4[1] = cv0[ks][1]; a0.u4[2] = cv0[ks][2]; a0.u4[3] = cv0[ks][3];
      a1.u4[0] = cv1[ks][0]; a1.u4[1] = cv1[ks][1]; a1.u4[2] = cv1[ks][2]; a1.u4[3] = cv1[ks][3];
      MFMA32(oa00, a0.v, v0);
      MFMA32(oa01, a0.v, v1);
      MFMA32(oa10, a1.v, v0);
      MFMA32(oa11, a1.v, v1);
    }
    __builtin_amdgcn_s_setprio(0);

    __syncthreads();  // drains vmcnt (prefetch landed) + lgkm; flips buffer
  }

  // epilogue: combine lane-halves of l; store un-normalized partials + lsums
  lsum0 += __shfl_xor(lsum0, 32);
  lsum1 += __shfl_xor(lsum1, 32);
  float* ls = half ? lsB : lsA;
  if (hi == 0) {
    ls[bh * 2048 + q0 + l31]      = lsum0;   // rows q0..q0+31
    ls[bh * 2048 + q0 + 32 + l31] = lsum1;   // rows q0+32..q0+63
  }
  int bb = bh >> 4, hh = bh & 15;
  size_t obase = ((size_t)bb * SEQ + q0) * 1024 + (size_t)hh * 64;
  #pragma unroll
  for (int r = 0; r < 16; ++r) {
    int qrw = (r & 3) + 8 * (r >> 2) + 4 * hi;    // C/D row within 32
    size_t b0 = obase + (size_t)qrw * 1024;
    size_t b1 = obase + (size_t)(32 + qrw) * 1024;
    if (half == 0) {
      pA[b0 + l31]      = oa00[r];
      pA[b0 + 32 + l31] = oa01[r];
      pA[b1 + l31]      = oa10[r];
      pA[b1 + 32 + l31] = oa11[r];
    } else {
      pB[b0 + l31]      = (bf16)oa00[r];
      pB[b0 + 32 + l31] = (bf16)oa01[r];
      pB[b1 + l31]      = (bf16)oa10[r];
      pB[b1 + 32 + l31] = (bf16)oa11[r];
    }
  }
}

// ---------- combine: ob = (pA + pB) / (lsA + lsB), in-place over pB ----------
__global__ __launch_bounds__(256) void attn_combine(
    const float* __restrict__ pA, const bf16* __restrict__ pBr,
    const float* __restrict__ lsA, const float* __restrict__ lsB,
    bf16* __restrict__ ob)
{
  size_t c = (size_t)blockIdx.x * 256 + threadIdx.x;  // 4-elem chunk id
  size_t i = c * 4;
  int b = (int)(i >> 21);
  int s = (int)((i >> 10) & 2047);
  int h = (int)((i >> 6) & 15);
  int li = (b * 16 + h) * 2048 + s;
  float inv = 1.0f / (lsA[li] + lsB[li]);
  float4 a = *(const float4*)(pA + i);
  bf16x4 bq = *(const bf16x4*)(pBr + i);
  bf16x4 o;
  o[0] = (bf16)((a.x + (float)bq[0]) * inv);
  o[1] = (bf16)((a.y + (float)bq[1]) * inv);
  o[2] = (bf16)((a.z + (float)bq[2]) * inv);
  o[3] = (bf16)((a.w + (float)bq[3]) * inv);
  *(bf16x4*)(ob + i) = o;   // same address as pBr[i]: per-thread in-place, safe
}

extern "C" void kernel_launch(void* const* d_in, const int* in_sizes, int n_in,
                              void* d_out, int out_size, void* d_ws, size_t ws_size,
                              hipStream_t stream) {
  const float* x   = (const float*)d_in[0];
  const float* wq  = (const float*)d_in[1];
  const float* wk  = (const float*)d_in[2];
  const float* wv  = (const float*)d_in[3];
  const float* wo  = (const float*)d_in[4];
  const float* bo  = (const float*)d_in[5];
  const float* gx  = (const float*)d_in[6];
  const float* bx  = (const float*)d_in[7];
  const float* gf  = (const float*)d_in[8];
  const float* bfp = (const float*)d_in[9];
  const float* w1  = (const float*)d_in[10];
  const float* b1  = (const float*)d_in[11];
  const float* w2  = (const float*)d_in[12];
  const float* b2  = (const float*)d_in[13];

  char* ws = (char*)d_ws;
  const size_t MB = 1024 * 1024;
  bf16*  wT  = (bf16*)ws;                // 6 x 2MB bf16 transposed weights
  bf16*  xs  = (bf16*)(ws + 12 * MB);    // LN1 out (dead after QKV)
  bf16*  qb  = (bf16*)(ws + 28 * MB);    // q,k,vt contiguous (dead after attn)
  bf16*  kb  = (bf16*)(ws + 44 * MB);
  bf16*  vtb = (bf16*)(ws + 60 * MB);
  // attn scratch (regions dead during attention):
  float* pA  = (float*)d_out;            // f32 partial (half 0), 32 MiB
  bf16*  pB  = (bf16*)(ws + 12 * MB);    // bf16 partial (half 1) over xs, 16 MiB
  float* lsA = (float*)ws;               // 0.5 MiB over dead wq^T
  float* lsB = (float*)(ws + 524288);    // 0.5 MiB
  bf16*  ob  = (bf16*)(ws + 12 * MB);    // combined attn out (in-place over pB)
  float* xt  = (float*)(ws + 28 * MB);   // residual fp32, reuses q+k (32 MiB)
  bf16*  hb  = (bf16*)(ws + 60 * MB);    // LN2 out, reuses vt
  bf16*  a1  = (bf16*)(ws + 12 * MB);    // FFN mid, reuses ob
  float* out = (float*)d_out;

  prep_w<<<1536, 256, 0, stream>>>(wq, wk, wv, wo, w1, w2, wT);
  ln_k<<<8192, 256, 0, stream>>>(x, gx, bx, xs);
  gemm_k<0, 24><<<1536, 256, 0, stream>>>(xs, wT, nullptr, nullptr, nullptr, qb);
  attn_k<<<1024, 256, 0, stream>>>(qb, kb, vtb, pA, pB, lsA, lsB);
  attn_combine<<<8192, 256, 0, stream>>>(pA, pB, lsA, lsB, ob);
  gemm_k<2, 8><<<512, 256, 0, stream>>>(ob, wT + (size_t)3 * MB, bo, x, xt, nullptr);
  ln_k<<<8192, 256, 0, stream>>>(xt, gf, bfp, hb);
  gemm_k<3, 8><<<512, 256, 0, stream>>>(hb, wT + (size_t)4 * MB, b1, nullptr, nullptr, a1);
  gemm_k<2, 8><<<512, 256, 0, stream>>>(a1, wT + (size_t)5 * MB, b2, xt, out, nullptr);
}

// Round 11
// 281.003 us; speedup vs baseline: 2.4066x; 1.0129x over previous
//
#include <hip/hip_runtime.h>
#include <hip/hip_bf16.h>

typedef __bf16 bf16;
typedef bf16 bf16x8 __attribute__((ext_vector_type(8)));
typedef bf16 bf16x4 __attribute__((ext_vector_type(4)));
typedef float f32x4 __attribute__((ext_vector_type(4)));
typedef float f32x16 __attribute__((ext_vector_type(16)));

#define AS1 __attribute__((address_space(1)))
#define AS3 __attribute__((address_space(3)))

static constexpr int SEQ = 2048;
static constexpr int NH  = 16;
static constexpr int DH  = 64;
static constexpr float SCLQ = 0.125f * 1.44269504088896340736f; // 1/sqrt(64)*log2(e)

__device__ __forceinline__ void gload16(const void* g, void* l) {
  __builtin_amdgcn_global_load_lds((const AS1 void*)g, (AS3 void*)l, 16, 0, 0);
}

__device__ __forceinline__ unsigned pk2(float a, float b) {
  union { bf16 h[2]; unsigned u; } z;
  z.h[0] = (bf16)a; z.h[1] = (bf16)b;
  return z.u;
}

// v_permlane32_swap_b32: a.upper32lanes <-> b.lower32lanes
__device__ __forceinline__ void plswap(unsigned &a, unsigned &b) {
  asm volatile("v_permlane32_swap_b32 %0, %1" : "+v"(a), "+v"(b));
}

#define MFMA32(d, a, b) d = __builtin_amdgcn_mfma_f32_32x32x16_bf16(a, b, d, 0, 0, 0)

// ---------- weight transpose + fp32->bf16 : Wt[n][k] = W[k][n] ----------
__global__ __launch_bounds__(256) void prep_w(
    const float* __restrict__ w0, const float* __restrict__ w1,
    const float* __restrict__ w2, const float* __restrict__ w3,
    const float* __restrict__ w4, const float* __restrict__ w5,
    bf16* __restrict__ dst)
{
  __shared__ float tile[64][65];
  int bid = blockIdx.x;
  int wi = bid >> 8;
  int tl = bid & 255;
  int tk = (tl >> 4) << 6;
  int tn = (tl & 15) << 6;
  const float* W = w0;
  if (wi == 1) W = w1; else if (wi == 2) W = w2; else if (wi == 3) W = w3;
  else if (wi == 4) W = w4; else if (wi == 5) W = w5;
  int t = threadIdx.x;
  #pragma unroll
  for (int rep = 0; rep < 16; ++rep) {
    int idx = rep * 256 + t;
    int i = idx >> 6, j = idx & 63;
    tile[i][j] = W[(size_t)(tk + i) * 1024 + tn + j];
  }
  __syncthreads();
  bf16* out = dst + (size_t)wi * 1024 * 1024;
  #pragma unroll
  for (int rep = 0; rep < 16; ++rep) {
    int idx = rep * 256 + t;
    int i = idx >> 6, j = idx & 63;
    out[(size_t)(tn + i) * 1024 + tk + j] = (bf16)tile[j][i];
  }
}

// ---------- LayerNorm: fp32 in -> bf16 out (one row per block) ----------
__global__ __launch_bounds__(256) void ln_k(
    const float* __restrict__ x, const float* __restrict__ g,
    const float* __restrict__ bb, bf16* __restrict__ out)
{
  int row = blockIdx.x;
  int t = threadIdx.x;
  float4 v = ((const float4*)(x + (size_t)row * 1024))[t];
  float s  = v.x + v.y + v.z + v.w;
  float s2 = v.x * v.x + v.y * v.y + v.z * v.z + v.w * v.w;
  #pragma unroll
  for (int m = 1; m < 64; m <<= 1) { s += __shfl_xor(s, m); s2 += __shfl_xor(s2, m); }
  __shared__ float red[8];
  int w = t >> 6;
  if ((t & 63) == 0) { red[w] = s; red[4 + w] = s2; }
  __syncthreads();
  s  = red[0] + red[1] + red[2] + red[3];
  s2 = red[4] + red[5] + red[6] + red[7];
  float mu  = s * (1.0f / 1024.0f);
  float var = s2 * (1.0f / 1024.0f) - mu * mu;
  float rst = rsqrtf(var + 1e-5f);
  float4 gv = ((const float4*)g)[t];
  float4 bv = ((const float4*)bb)[t];
  bf16x4 o;
  o[0] = (bf16)((v.x - mu) * rst * gv.x + bv.x);
  o[1] = (bf16)((v.y - mu) * rst * gv.y + bv.y);
  o[2] = (bf16)((v.z - mu) * rst * gv.z + bv.z);
  o[3] = (bf16)((v.w - mu) * rst * gv.w + bv.w);
  *(bf16x4*)(out + (size_t)row * 1024 + t * 4) = o;
}

// ---------- GEMM: C[M=8192][N=NT*128] = A[M][1024] * Bt[N][1024]^T ----------
// m97 structure (round-3 verified): 128x128 tile, BK=64, 4 waves.
template<int EPI, int NT>
__global__ __launch_bounds__(256) void gemm_k(
    const bf16* __restrict__ A, const bf16* __restrict__ Bt,
    const float* __restrict__ bias, const float* __restrict__ res,
    float* __restrict__ outf, bf16* __restrict__ outb)
{
  __shared__ bf16 lA[128 * 64];
  __shared__ bf16 lB[128 * 64];
  int t = threadIdx.x;
  int wg = blockIdx.x;
  int swz = (wg & 7) * (NT * 8) + (wg >> 3);   // XCD-bijective swizzle
  int mt = swz / NT, nt = swz % NT;
  int lane = t & 63, w = t >> 6;
  int l16 = lane & 15, lh = lane >> 4;
  int wr = w >> 1, wc = w & 1;

  f32x4 acc[4][4] = {};
  const size_t mbase = (size_t)mt * 128;
  const size_t nbase = (size_t)nt * 128;
  int u = t & 7;

  for (int ks = 0; ks < 16; ++ks) {
    int k0 = ks * 64;
    #pragma unroll
    for (int i = 0; i < 4; ++i) {
      int row = i * 32 + (t >> 3);
      int up = u ^ (row & 7);
      gload16(A  + (mbase + row) * 1024 + k0 + up * 8, lA + i * 2048 + w * 512);
      gload16(Bt + (nbase + row) * 1024 + k0 + up * 8, lB + i * 2048 + w * 512);
    }
    __syncthreads();
    #pragma unroll
    for (int kc = 0; kc < 2; ++kc) {
      bf16x8 af[4], bfr[4];
      #pragma unroll
      for (int mi = 0; mi < 4; ++mi) {
        int row = wr * 64 + mi * 16 + l16;
        af[mi] = *(const bf16x8*)(lA + row * 64 + (((kc * 4 + lh) ^ (row & 7)) * 8));
      }
      #pragma unroll
      for (int ni = 0; ni < 4; ++ni) {
        int row = wc * 64 + ni * 16 + l16;
        bfr[ni] = *(const bf16x8*)(lB + row * 64 + (((kc * 4 + lh) ^ (row & 7)) * 8));
      }
      #pragma unroll
      for (int mi = 0; mi < 4; ++mi)
        #pragma unroll
        for (int ni = 0; ni < 4; ++ni)
          acc[mi][ni] = __builtin_amdgcn_mfma_f32_16x16x32_bf16(af[mi], bfr[ni], acc[mi][ni], 0, 0, 0);
    }
    __syncthreads();
  }

  int mrow0 = mt * 128 + wr * 64;
  int ncol0 = nt * 128 + wc * 64;
  #pragma unroll
  for (int mi = 0; mi < 4; ++mi) {
    #pragma unroll
    for (int ni = 0; ni < 4; ++ni) {
      if constexpr (EPI == 0) {
        int gcol = ncol0 + ni * 16 + l16;
        int which = gcol >> 10;                  // 0=q 1=k 2=v
        int col = gcol & 1023;
        int h = col >> 6, dh = col & 63;
        bf16* dst = outb + (size_t)which * (size_t)(4 * NH * SEQ * DH);
        if (which == 2) {
          int s0 = mrow0 + mi * 16 + lh * 4;
          int b = s0 >> 11, s = s0 & 2047;
          bf16x4 pkv;
          #pragma unroll
          for (int r = 0; r < 4; ++r) pkv[r] = (bf16)acc[mi][ni][r];
          *(bf16x4*)(dst + (((size_t)((b * NH + h) * DH + dh)) << 11) + s) = pkv;
        } else {
          #pragma unroll
          for (int r = 0; r < 4; ++r) {
            int grow = mrow0 + mi * 16 + lh * 4 + r;
            int b = grow >> 11, s = grow & 2047;
            float v = acc[mi][ni][r];
            if (which == 0) v *= SCLQ;           // fold softmax scale into q
            dst[(((size_t)((b * NH + h) * SEQ + s)) << 6) + dh] = (bf16)v;
          }
        }
      } else {
        #pragma unroll
        for (int r = 0; r < 4; ++r) {
          int grow = mrow0 + mi * 16 + lh * 4 + r;
          int gcol = ncol0 + ni * 16 + l16;
          float v = acc[mi][ni][r];
          if constexpr (EPI == 2) {
            size_t idx = (size_t)grow * 1024 + gcol;
            outf[idx] = v + bias[gcol] + res[idx];
          } else {
            size_t idx = (size_t)grow * 1024 + gcol;
            float z = v + bias[gcol];
            outb[idx] = (bf16)(z > 0.f ? z : 0.f);
          }
        }
      }
    }
  }
}

// ---------- flash attention, occupancy-targeted ----------
// 1 q-tile (32 rows) per wave; 64-key tile processed as two key-halves with
// split S-accumulators (only 16 live) and immediate PV per half. Natural
// combined VGPR+AGPR ~110 <= 128, so __launch_bounds__(256,4) holds 4 waves/SIMD
// = 4 blocks/CU (grid 1024) without spill. Static m=0 softmax (q pre-scaled).
__global__ __launch_bounds__(256, 4) void attn_k(
    const bf16* __restrict__ q, const bf16* __restrict__ kk,
    const bf16* __restrict__ vt, bf16* __restrict__ o)
{
  __shared__ bf16 lK[2][4096];   // [key 0..63][dh 0..63], unit-swizzled
  __shared__ bf16 lV[2][4096];   // [dh 0..63][key 0..63], unit-swizzled

  int t = threadIdx.x;
  int lane = t & 63, w = t >> 6;
  int l31 = lane & 31, hi = lane >> 5;
  int bid = blockIdx.x;
  int swz = (bid & 7) * 128 + (bid >> 3);   // XCD-bijective (1024 = 8*128)
  int bh = swz >> 4, qt = swz & 15;
  int q0 = qt * 128 + w * 32;
  size_t bhS = (size_t)bh * SEQ;

  // Q fragments (B-operand): lane holds q = q0+l31, dh = ks*16 + hi*8 + j
  const bf16* qrow = q + (bhS + q0 + l31) * 64 + hi * 8;
  bf16x8 aq[4];
  #pragma unroll
  for (int ks = 0; ks < 4; ++ks) aq[ks] = *(const bf16x8*)(qrow + ks * 16);

  // staging source addresses (per-lane, pre-swizzled on the 16B unit)
  int srow = t >> 3;
  int u8 = (t & 7) ^ (srow & 7);
  const bf16* kSrc = kk + (bhS + srow) * 64 + u8 * 8;
  const bf16* vSrc = vt + ((size_t)bh * 64 + srow) * SEQ + u8 * 8;

  f32x16 oa0 = {}, oa1 = {};
  float lsum = 0.f;

  // prologue: stage tile 0 into buffer 0
  gload16(kSrc,            &lK[0][w * 512]);
  gload16(kSrc + 2048,     &lK[0][2048 + w * 512]);
  gload16(vSrc,            &lV[0][w * 512]);
  gload16(vSrc + 32 * SEQ, &lV[0][2048 + w * 512]);
  __syncthreads();

  #pragma unroll 2
  for (int kt = 0; kt < 32; ++kt) {
    const int cur = kt & 1;
    // prefetch next tile into the other buffer (issue before compute)
    if (kt < 31) {
      const bf16* ks2 = kSrc + (size_t)(kt + 1) * 4096;
      const bf16* vs2 = vSrc + (kt + 1) * 64;
      gload16(ks2,            &lK[cur ^ 1][w * 512]);
      gload16(ks2 + 2048,     &lK[cur ^ 1][2048 + w * 512]);
      gload16(vs2,            &lV[cur ^ 1][w * 512]);
      gload16(vs2 + 32 * SEQ, &lV[cur ^ 1][2048 + w * 512]);
    }

    const bf16* bK = &lK[cur][0];
    const bf16* bV = &lV[cur][0];

    // ---- key-half A (keys 0..31): QK -> softmax -> PV ----
    {
      f32x16 s = {};
      __builtin_amdgcn_s_setprio(1);
      #pragma unroll
      for (int ks = 0; ks < 4; ++ks) {
        int u = ((2 * ks + hi) ^ (l31 & 7)) * 8;
        bf16x8 k0 = *(const bf16x8*)(bK + l31 * 64 + u);
        MFMA32(s, k0, aq[ks]);
      }
      __builtin_amdgcn_s_setprio(0);
      float p[16];
      #pragma unroll
      for (int i = 0; i < 16; ++i) p[i] = __builtin_amdgcn_exp2f(s[i]);
      float t8[4];
      #pragma unroll
      for (int i = 0; i < 4; ++i)
        t8[i] = (p[4 * i] + p[4 * i + 1]) + (p[4 * i + 2] + p[4 * i + 3]);
      lsum += (t8[0] + t8[1]) + (t8[2] + t8[3]);
      unsigned cv[2][4];
      #pragma unroll
      for (int g2 = 0; g2 < 2; ++g2) {
        int g = 8 * g2;
        unsigned X0 = pk2(p[g],     p[g + 1]), X1 = pk2(p[g + 2], p[g + 3]);
        unsigned Y0 = pk2(p[g + 4], p[g + 5]), Y1 = pk2(p[g + 6], p[g + 7]);
        plswap(X0, Y0); plswap(X1, Y1);
        cv[g2][0] = X0; cv[g2][1] = X1; cv[g2][2] = Y0; cv[g2][3] = Y1;
      }
      __builtin_amdgcn_s_setprio(1);
      #pragma unroll
      for (int ks = 0; ks < 2; ++ks) {
        int u = ((2 * ks + hi) ^ (l31 & 7)) * 8;
        bf16x8 v0 = *(const bf16x8*)(bV + l31 * 64 + u);
        bf16x8 v1 = *(const bf16x8*)(bV + (32 + l31) * 64 + u);
        union { unsigned u4[4]; bf16x8 v; } a;
        a.u4[0] = cv[ks][0]; a.u4[1] = cv[ks][1]; a.u4[2] = cv[ks][2]; a.u4[3] = cv[ks][3];
        MFMA32(oa0, a.v, v0);
        MFMA32(oa1, a.v, v1);
      }
      __builtin_amdgcn_s_setprio(0);
    }

    // ---- key-half B (keys 32..63): QK -> softmax -> PV ----
    {
      f32x16 s = {};
      __builtin_amdgcn_s_setprio(1);
      #pragma unroll
      for (int ks = 0; ks < 4; ++ks) {
        int u = ((2 * ks + hi) ^ (l31 & 7)) * 8;
        bf16x8 k1 = *(const bf16x8*)(bK + (32 + l31) * 64 + u);
        MFMA32(s, k1, aq[ks]);
      }
      __builtin_amdgcn_s_setprio(0);
      float p[16];
      #pragma unroll
      for (int i = 0; i < 16; ++i) p[i] = __builtin_amdgcn_exp2f(s[i]);
      float t8[4];
      #pragma unroll
      for (int i = 0; i < 4; ++i)
        t8[i] = (p[4 * i] + p[4 * i + 1]) + (p[4 * i + 2] + p[4 * i + 3]);
      lsum += (t8[0] + t8[1]) + (t8[2] + t8[3]);
      unsigned cv[2][4];
      #pragma unroll
      for (int g2 = 0; g2 < 2; ++g2) {
        int g = 8 * g2;
        unsigned X0 = pk2(p[g],     p[g + 1]), X1 = pk2(p[g + 2], p[g + 3]);
        unsigned Y0 = pk2(p[g + 4], p[g + 5]), Y1 = pk2(p[g + 6], p[g + 7]);
        plswap(X0, Y0); plswap(X1, Y1);
        cv[g2][0] = X0; cv[g2][1] = X1; cv[g2][2] = Y0; cv[g2][3] = Y1;
      }
      __builtin_amdgcn_s_setprio(1);
      #pragma unroll
      for (int ks = 2; ks < 4; ++ks) {
        int u = ((2 * ks + hi) ^ (l31 & 7)) * 8;
        bf16x8 v0 = *(const bf16x8*)(bV + l31 * 64 + u);
        bf16x8 v1 = *(const bf16x8*)(bV + (32 + l31) * 64 + u);
        union { unsigned u4[4]; bf16x8 v; } a;
        a.u4[0] = cv[ks - 2][0]; a.u4[1] = cv[ks - 2][1];
        a.u4[2] = cv[ks - 2][2]; a.u4[3] = cv[ks - 2][3];
        MFMA32(oa0, a.v, v0);
        MFMA32(oa1, a.v, v1);
      }
      __builtin_amdgcn_s_setprio(0);
    }

    __syncthreads();  // drains vmcnt (prefetch landed) + lgkm; flips buffer
  }

  // epilogue: combine halves of l, broadcast 1/l to O rows, store
  lsum += __shfl_xor(lsum, 32);
  float inv = 1.0f / lsum;                    // valid for q = q0 + l31
  int bb = bh >> 4, hh = bh & 15;
  size_t obase = ((size_t)bb * SEQ + q0) * 1024 + (size_t)hh * 64;
  #pragma unroll
  for (int r = 0; r < 16; ++r) {
    int qrw = (r & 3) + 8 * (r >> 2) + 4 * hi;    // C/D row within 32
    float iv = __shfl(inv, qrw);
    size_t base = obase + (size_t)qrw * 1024;
    o[base + l31]      = (bf16)(oa0[r] * iv);
    o[base + 32 + l31] = (bf16)(oa1[r] * iv);
  }
}

extern "C" void kernel_launch(void* const* d_in, const int* in_sizes, int n_in,
                              void* d_out, int out_size, void* d_ws, size_t ws_size,
                              hipStream_t stream) {
  const float* x   = (const float*)d_in[0];
  const float* wq  = (const float*)d_in[1];
  const float* wk  = (const float*)d_in[2];
  const float* wv  = (const float*)d_in[3];
  const float* wo  = (const float*)d_in[4];
  const float* bo  = (const float*)d_in[5];
  const float* gx  = (const float*)d_in[6];
  const float* bx  = (const float*)d_in[7];
  const float* gf  = (const float*)d_in[8];
  const float* bfp = (const float*)d_in[9];
  const float* w1  = (const float*)d_in[10];
  const float* b1  = (const float*)d_in[11];
  const float* w2  = (const float*)d_in[12];
  const float* b2  = (const float*)d_in[13];

  char* ws = (char*)d_ws;
  const size_t MB = 1024 * 1024;
  bf16*  wT  = (bf16*)ws;                // 6 x 2MB bf16 transposed weights
  bf16*  xs  = (bf16*)(ws + 12 * MB);    // LN1 out          (dead after QKV)
  bf16*  qb  = (bf16*)(ws + 28 * MB);    // q,k,vt contiguous (dead after attn)
  bf16*  kb  = (bf16*)(ws + 44 * MB);
  bf16*  vtb = (bf16*)(ws + 60 * MB);
  bf16*  ob  = (bf16*)(ws + 12 * MB);    // attn out, reuses xs
  float* xt  = (float*)(ws + 28 * MB);   // residual fp32, reuses q+k
  bf16*  hb  = (bf16*)(ws + 60 * MB);    // LN2 out, reuses vt
  bf16*  a1  = (bf16*)(ws + 12 * MB);    // FFN mid, reuses ob
  float* out = (float*)d_out;

  prep_w<<<1536, 256, 0, stream>>>(wq, wk, wv, wo, w1, w2, wT);
  ln_k<<<8192, 256, 0, stream>>>(x, gx, bx, xs);
  gemm_k<0, 24><<<1536, 256, 0, stream>>>(xs, wT, nullptr, nullptr, nullptr, qb);
  attn_k<<<1024, 256, 0, stream>>>(qb, kb, vtb, ob);
  gemm_k<2, 8><<<512, 256, 0, stream>>>(ob, wT + (size_t)3 * MB, bo, x, xt, nullptr);
  ln_k<<<8192, 256, 0, stream>>>(xt, gf, bfp, hb);
  gemm_k<3, 8><<<512, 256, 0, stream>>>(hb, wT + (size_t)4 * MB, b1, nullptr, nullptr, a1);
  gemm_k<2, 8><<<512, 256, 0, stream>>>(a1, wT + (size_t)5 * MB, b2, xt, out, nullptr);
}

// Round 12
// 271.385 us; speedup vs baseline: 2.4919x; 1.0354x over previous
//
#include <hip/hip_runtime.h>
#include <hip/hip_bf16.h>

typedef __bf16 bf16;
typedef bf16 bf16x8 __attribute__((ext_vector_type(8)));
typedef bf16 bf16x4 __attribute__((ext_vector_type(4)));
typedef float f32x4 __attribute__((ext_vector_type(4)));
typedef float f32x16 __attribute__((ext_vector_type(16)));

#define AS1 __attribute__((address_space(1)))
#define AS3 __attribute__((address_space(3)))

static constexpr int SEQ = 2048;
static constexpr int NH  = 16;
static constexpr int DH  = 64;
static constexpr float SCLQ = 0.125f * 1.44269504088896340736f; // 1/sqrt(64)*log2(e)

__device__ __forceinline__ void gload16(const void* g, void* l) {
  __builtin_amdgcn_global_load_lds((const AS1 void*)g, (AS3 void*)l, 16, 0, 0);
}

__device__ __forceinline__ unsigned pk2(float a, float b) {
  union { bf16 h[2]; unsigned u; } z;
  z.h[0] = (bf16)a; z.h[1] = (bf16)b;
  return z.u;
}

// v_permlane32_swap_b32: a.upper32lanes <-> b.lower32lanes
__device__ __forceinline__ void plswap(unsigned &a, unsigned &b) {
  asm volatile("v_permlane32_swap_b32 %0, %1" : "+v"(a), "+v"(b));
}

#define MFMA32(d, a, b) d = __builtin_amdgcn_mfma_f32_32x32x16_bf16(a, b, d, 0, 0, 0)

// ---------- weight transpose + fp32->bf16 : Wt[n][k] = W[k][n] ----------
__global__ __launch_bounds__(256) void prep_w(
    const float* __restrict__ w0, const float* __restrict__ w1,
    const float* __restrict__ w2, const float* __restrict__ w3,
    const float* __restrict__ w4, const float* __restrict__ w5,
    bf16* __restrict__ dst)
{
  __shared__ float tile[64][65];
  int bid = blockIdx.x;
  int wi = bid >> 8;
  int tl = bid & 255;
  int tk = (tl >> 4) << 6;
  int tn = (tl & 15) << 6;
  const float* W = w0;
  if (wi == 1) W = w1; else if (wi == 2) W = w2; else if (wi == 3) W = w3;
  else if (wi == 4) W = w4; else if (wi == 5) W = w5;
  int t = threadIdx.x;
  #pragma unroll
  for (int rep = 0; rep < 16; ++rep) {
    int idx = rep * 256 + t;
    int i = idx >> 6, j = idx & 63;
    tile[i][j] = W[(size_t)(tk + i) * 1024 + tn + j];
  }
  __syncthreads();
  bf16* out = dst + (size_t)wi * 1024 * 1024;
  #pragma unroll
  for (int rep = 0; rep < 16; ++rep) {
    int idx = rep * 256 + t;
    int i = idx >> 6, j = idx & 63;
    out[(size_t)(tn + i) * 1024 + tk + j] = (bf16)tile[j][i];
  }
}

// ---------- LayerNorm: fp32 in -> bf16 out (one row per block) ----------
__global__ __launch_bounds__(256) void ln_k(
    const float* __restrict__ x, const float* __restrict__ g,
    const float* __restrict__ bb, bf16* __restrict__ out)
{
  int row = blockIdx.x;
  int t = threadIdx.x;
  float4 v = ((const float4*)(x + (size_t)row * 1024))[t];
  float s  = v.x + v.y + v.z + v.w;
  float s2 = v.x * v.x + v.y * v.y + v.z * v.z + v.w * v.w;
  #pragma unroll
  for (int m = 1; m < 64; m <<= 1) { s += __shfl_xor(s, m); s2 += __shfl_xor(s2, m); }
  __shared__ float red[8];
  int w = t >> 6;
  if ((t & 63) == 0) { red[w] = s; red[4 + w] = s2; }
  __syncthreads();
  s  = red[0] + red[1] + red[2] + red[3];
  s2 = red[4] + red[5] + red[6] + red[7];
  float mu  = s * (1.0f / 1024.0f);
  float var = s2 * (1.0f / 1024.0f) - mu * mu;
  float rst = rsqrtf(var + 1e-5f);
  float4 gv = ((const float4*)g)[t];
  float4 bv = ((const float4*)bb)[t];
  bf16x4 o;
  o[0] = (bf16)((v.x - mu) * rst * gv.x + bv.x);
  o[1] = (bf16)((v.y - mu) * rst * gv.y + bv.y);
  o[2] = (bf16)((v.z - mu) * rst * gv.z + bv.z);
  o[3] = (bf16)((v.w - mu) * rst * gv.w + bv.w);
  *(bf16x4*)(out + (size_t)row * 1024 + t * 4) = o;
}

// ---------- GEMM: C[M=8192][N=NT*128] = A[M][1024] * Bt[N][1024]^T ----------
// m97 structure (round-3 verified): 128x128 tile, BK=64, 4 waves.
// EPI 0: fused QKV -> q (pre-scaled by SCLQ) / k (B,H,S,Dh) + v^T (B,H,Dh,S)
// EPI 2: out fp32 = acc + bias[col] + res[row][col]
// EPI 3: out bf16 = relu(acc + bias[col])
template<int EPI, int NT>
__global__ __launch_bounds__(256) void gemm_k(
    const bf16* __restrict__ A, const bf16* __restrict__ Bt,
    const float* __restrict__ bias, const float* __restrict__ res,
    float* __restrict__ outf, bf16* __restrict__ outb)
{
  __shared__ bf16 lA[128 * 64];
  __shared__ bf16 lB[128 * 64];
  int t = threadIdx.x;
  int wg = blockIdx.x;
  int swz = (wg & 7) * (NT * 8) + (wg >> 3);   // XCD-bijective swizzle
  int mt = swz / NT, nt = swz % NT;
  int lane = t & 63, w = t >> 6;
  int l16 = lane & 15, lh = lane >> 4;
  int wr = w >> 1, wc = w & 1;

  f32x4 acc[4][4] = {};
  const size_t mbase = (size_t)mt * 128;
  const size_t nbase = (size_t)nt * 128;
  int u = t & 7;

  for (int ks = 0; ks < 16; ++ks) {
    int k0 = ks * 64;
    #pragma unroll
    for (int i = 0; i < 4; ++i) {
      int row = i * 32 + (t >> 3);
      int up = u ^ (row & 7);
      gload16(A  + (mbase + row) * 1024 + k0 + up * 8, lA + i * 2048 + w * 512);
      gload16(Bt + (nbase + row) * 1024 + k0 + up * 8, lB + i * 2048 + w * 512);
    }
    __syncthreads();
    #pragma unroll
    for (int kc = 0; kc < 2; ++kc) {
      bf16x8 af[4], bfr[4];
      #pragma unroll
      for (int mi = 0; mi < 4; ++mi) {
        int row = wr * 64 + mi * 16 + l16;
        af[mi] = *(const bf16x8*)(lA + row * 64 + (((kc * 4 + lh) ^ (row & 7)) * 8));
      }
      #pragma unroll
      for (int ni = 0; ni < 4; ++ni) {
        int row = wc * 64 + ni * 16 + l16;
        bfr[ni] = *(const bf16x8*)(lB + row * 64 + (((kc * 4 + lh) ^ (row & 7)) * 8));
      }
      #pragma unroll
      for (int mi = 0; mi < 4; ++mi)
        #pragma unroll
        for (int ni = 0; ni < 4; ++ni)
          acc[mi][ni] = __builtin_amdgcn_mfma_f32_16x16x32_bf16(af[mi], bfr[ni], acc[mi][ni], 0, 0, 0);
    }
    __syncthreads();
  }

  int mrow0 = mt * 128 + wr * 64;
  int ncol0 = nt * 128 + wc * 64;
  #pragma unroll
  for (int mi = 0; mi < 4; ++mi) {
    #pragma unroll
    for (int ni = 0; ni < 4; ++ni) {
      if constexpr (EPI == 0) {
        int gcol = ncol0 + ni * 16 + l16;
        int which = gcol >> 10;                  // 0=q 1=k 2=v
        int col = gcol & 1023;
        int h = col >> 6, dh = col & 63;
        bf16* dst = outb + (size_t)which * (size_t)(4 * NH * SEQ * DH);
        if (which == 2) {
          // V^T: 4 consecutive s per lane -> one 8B store
          int s0 = mrow0 + mi * 16 + lh * 4;
          int b = s0 >> 11, s = s0 & 2047;
          bf16x4 pkv;
          #pragma unroll
          for (int r = 0; r < 4; ++r) pkv[r] = (bf16)acc[mi][ni][r];
          *(bf16x4*)(dst + (((size_t)((b * NH + h) * DH + dh)) << 11) + s) = pkv;
        } else {
          #pragma unroll
          for (int r = 0; r < 4; ++r) {
            int grow = mrow0 + mi * 16 + lh * 4 + r;
            int b = grow >> 11, s = grow & 2047;
            float v = acc[mi][ni][r];
            if (which == 0) v *= SCLQ;           // fold softmax scale into q
            dst[(((size_t)((b * NH + h) * SEQ + s)) << 6) + dh] = (bf16)v;
          }
        }
      } else {
        #pragma unroll
        for (int r = 0; r < 4; ++r) {
          int grow = mrow0 + mi * 16 + lh * 4 + r;
          int gcol = ncol0 + ni * 16 + l16;
          float v = acc[mi][ni][r];
          if constexpr (EPI == 2) {
            size_t idx = (size_t)grow * 1024 + gcol;
            outf[idx] = v + bias[gcol] + res[idx];
          } else {
            size_t idx = (size_t)grow * 1024 + gcol;
            float z = v + bias[gcol];
            outb[idx] = (bf16)(z > 0.f ? z : 0.f);
          }
        }
      }
    }
  }
}

// ---------- flash attention, swapped-QK 32x32, 2 q-tiles per wave ----------
// Session-best configuration (round 5): 512 blocks x 4 waves, 64 q-rows/wave,
// double-buffered K/V via global_load_lds, static m=0 softmax (q pre-scaled),
// pk2+permlane32_swap P-redistribution, 4 independent MFMA chains per wave.
__global__ __launch_bounds__(256, 2) void attn_k(
    const bf16* __restrict__ q, const bf16* __restrict__ kk,
    const bf16* __restrict__ vt, bf16* __restrict__ o)
{
  __shared__ bf16 lK[2][4096];   // [key 0..63][dh 0..63], unit-swizzled
  __shared__ bf16 lV[2][4096];   // [dh 0..63][key 0..63], unit-swizzled

  int t = threadIdx.x;
  int lane = t & 63, w = t >> 6;
  int l31 = lane & 31, hi = lane >> 5;
  int bid = blockIdx.x;
  int swz = (bid & 7) * 64 + (bid >> 3);   // 8 bh per XCD, all q-tiles local
  int bh = swz >> 3, qt = swz & 7;
  int q0 = qt * 256 + w * 64;
  size_t bhS = (size_t)bh * SEQ;

  // Q fragments (B-operand): lane holds q = base+l31, dh = ks*16 + hi*8 + j
  const bf16* qrow0 = q + (bhS + q0 + l31) * 64 + hi * 8;
  const bf16* qrow1 = qrow0 + 32 * 64;
  bf16x8 aq0[4], aq1[4];
  #pragma unroll
  for (int ks = 0; ks < 4; ++ks) {
    aq0[ks] = *(const bf16x8*)(qrow0 + ks * 16);
    aq1[ks] = *(const bf16x8*)(qrow1 + ks * 16);
  }

  // staging source addresses (per-lane, pre-swizzled on the 16B unit)
  int srow = t >> 3;
  int u8 = (t & 7) ^ (srow & 7);
  const bf16* kSrc = kk + (bhS + srow) * 64 + u8 * 8;
  const bf16* vSrc = vt + ((size_t)bh * 64 + srow) * SEQ + u8 * 8;

  f32x16 oa00 = {}, oa01 = {}, oa10 = {}, oa11 = {};
  float lsum0 = 0.f, lsum1 = 0.f;

  // prologue: stage tile 0 into buffer 0
  gload16(kSrc,            &lK[0][w * 512]);
  gload16(kSrc + 2048,     &lK[0][2048 + w * 512]);
  gload16(vSrc,            &lV[0][w * 512]);
  gload16(vSrc + 32 * SEQ, &lV[0][2048 + w * 512]);
  __syncthreads();

  #pragma unroll 2
  for (int kt = 0; kt < 32; ++kt) {
    const int cur = kt & 1;
    // prefetch next tile into the other buffer (issue before compute)
    if (kt < 31) {
      const bf16* ks2 = kSrc + (size_t)(kt + 1) * 4096;
      const bf16* vs2 = vSrc + (kt + 1) * 64;
      gload16(ks2,            &lK[cur ^ 1][w * 512]);
      gload16(ks2 + 2048,     &lK[cur ^ 1][2048 + w * 512]);
      gload16(vs2,            &lV[cur ^ 1][w * 512]);
      gload16(vs2 + 32 * SEQ, &lV[cur ^ 1][2048 + w * 512]);
    }

    const bf16* bK = &lK[cur][0];
    const bf16* bV = &lV[cur][0];

    // QK^T (swapped): 4 independent accumulator chains
    f32x16 sA0 = {}, sB0 = {}, sA1 = {}, sB1 = {};
    __builtin_amdgcn_s_setprio(1);
    #pragma unroll
    for (int ks = 0; ks < 4; ++ks) {
      int u = ((2 * ks + hi) ^ (l31 & 7)) * 8;
      bf16x8 k0 = *(const bf16x8*)(bK + l31 * 64 + u);
      bf16x8 k1 = *(const bf16x8*)(bK + (32 + l31) * 64 + u);
      MFMA32(sA0, k0, aq0[ks]);
      MFMA32(sA1, k0, aq1[ks]);
      MFMA32(sB0, k1, aq0[ks]);
      MFMA32(sB1, k1, aq1[ks]);
    }
    __builtin_amdgcn_s_setprio(0);

    // softmax (static m=0) + pack/swap into PV A-fragments, per q-tile
    unsigned cv0[4][4], cv1[4][4];
    {
      float p[32];
      #pragma unroll
      for (int i = 0; i < 16; ++i) {
        p[i]      = __builtin_amdgcn_exp2f(sA0[i]);
        p[16 + i] = __builtin_amdgcn_exp2f(sB0[i]);
      }
      float t8[8];
      #pragma unroll
      for (int i = 0; i < 8; ++i)
        t8[i] = (p[4 * i] + p[4 * i + 1]) + (p[4 * i + 2] + p[4 * i + 3]);
      lsum0 += ((t8[0] + t8[1]) + (t8[2] + t8[3])) + ((t8[4] + t8[5]) + (t8[6] + t8[7]));
      #pragma unroll
      for (int ks = 0; ks < 4; ++ks) {
        int g = 8 * ks;
        unsigned X0 = pk2(p[g],     p[g + 1]), X1 = pk2(p[g + 2], p[g + 3]);
        unsigned Y0 = pk2(p[g + 4], p[g + 5]), Y1 = pk2(p[g + 6], p[g + 7]);
        plswap(X0, Y0);
        plswap(X1, Y1);
        cv0[ks][0] = X0; cv0[ks][1] = X1; cv0[ks][2] = Y0; cv0[ks][3] = Y1;
      }
    }
    {
      float p[32];
      #pragma unroll
      for (int i = 0; i < 16; ++i) {
        p[i]      = __builtin_amdgcn_exp2f(sA1[i]);
        p[16 + i] = __builtin_amdgcn_exp2f(sB1[i]);
      }
      float t8[8];
      #pragma unroll
      for (int i = 0; i < 8; ++i)
        t8[i] = (p[4 * i] + p[4 * i + 1]) + (p[4 * i + 2] + p[4 * i + 3]);
      lsum1 += ((t8[0] + t8[1]) + (t8[2] + t8[3])) + ((t8[4] + t8[5]) + (t8[6] + t8[7]));
      #pragma unroll
      for (int ks = 0; ks < 4; ++ks) {
        int g = 8 * ks;
        unsigned X0 = pk2(p[g],     p[g + 1]), X1 = pk2(p[g + 2], p[g + 3]);
        unsigned Y0 = pk2(p[g + 4], p[g + 5]), Y1 = pk2(p[g + 6], p[g + 7]);
        plswap(X0, Y0);
        plswap(X1, Y1);
        cv1[ks][0] = X0; cv1[ks][1] = X1; cv1[ks][2] = Y0; cv1[ks][3] = Y1;
      }
    }

    // PV: 4 independent chains, shared V fragments
    __builtin_amdgcn_s_setprio(1);
    #pragma unroll
    for (int ks = 0; ks < 4; ++ks) {
      int u = ((2 * ks + hi) ^ (l31 & 7)) * 8;
      bf16x8 v0 = *(const bf16x8*)(bV + l31 * 64 + u);
      bf16x8 v1 = *(const bf16x8*)(bV + (32 + l31) * 64 + u);
      union { unsigned u4[4]; bf16x8 v; } a0, a1;
      a0.u4[0] = cv0[ks][0]; a0.u4[1] = cv0[ks][1]; a0.u4[2] = cv0[ks][2]; a0.u4[3] = cv0[ks][3];
      a1.u4[0] = cv1[ks][0]; a1.u4[1] = cv1[ks][1]; a1.u4[2] = cv1[ks][2]; a1.u4[3] = cv1[ks][3];
      MFMA32(oa00, a0.v, v0);
      MFMA32(oa01, a0.v, v1);
      MFMA32(oa10, a1.v, v0);
      MFMA32(oa11, a1.v, v1);
    }
    __builtin_amdgcn_s_setprio(0);

    __syncthreads();  // drains vmcnt (prefetch landed) + lgkm; flips buffer
  }

  // epilogue: combine halves of l, broadcast 1/l to O rows, store
  lsum0 += __shfl_xor(lsum0, 32);
  lsum1 += __shfl_xor(lsum1, 32);
  float inv0 = 1.0f / lsum0;                  // valid for q-row = l31 (tile 0)
  float inv1 = 1.0f / lsum1;                  // tile 1
  int bb = bh >> 4, hh = bh & 15;
  size_t obase = ((size_t)bb * SEQ + q0) * 1024 + (size_t)hh * 64;
  #pragma unroll
  for (int r = 0; r < 16; ++r) {
    int qrw = (r & 3) + 8 * (r >> 2) + 4 * hi;    // C/D row within 32
    float iv0 = __shfl(inv0, qrw);
    float iv1 = __shfl(inv1, qrw);
    size_t b0 = obase + (size_t)qrw * 1024;
    size_t b1 = obase + (size_t)(32 + qrw) * 1024;
    o[b0 + l31]      = (bf16)(oa00[r] * iv0);
    o[b0 + 32 + l31] = (bf16)(oa01[r] * iv0);
    o[b1 + l31]      = (bf16)(oa10[r] * iv1);
    o[b1 + 32 + l31] = (bf16)(oa11[r] * iv1);
  }
}

extern "C" void kernel_launch(void* const* d_in, const int* in_sizes, int n_in,
                              void* d_out, int out_size, void* d_ws, size_t ws_size,
                              hipStream_t stream) {
  const float* x   = (const float*)d_in[0];
  const float* wq  = (const float*)d_in[1];
  const float* wk  = (const float*)d_in[2];
  const float* wv  = (const float*)d_in[3];
  const float* wo  = (const float*)d_in[4];
  const float* bo  = (const float*)d_in[5];
  const float* gx  = (const float*)d_in[6];
  const float* bx  = (const float*)d_in[7];
  const float* gf  = (const float*)d_in[8];
  const float* bfp = (const float*)d_in[9];
  const float* w1  = (const float*)d_in[10];
  const float* b1  = (const float*)d_in[11];
  const float* w2  = (const float*)d_in[12];
  const float* b2  = (const float*)d_in[13];

  char* ws = (char*)d_ws;
  const size_t MB = 1024 * 1024;
  bf16*  wT  = (bf16*)ws;                // 6 x 2MB bf16 transposed weights
  bf16*  xs  = (bf16*)(ws + 12 * MB);    // LN1 out          (dead after QKV)
  bf16*  qb  = (bf16*)(ws + 28 * MB);    // q,k,vt contiguous (dead after attn)
  bf16*  kb  = (bf16*)(ws + 44 * MB);
  bf16*  vtb = (bf16*)(ws + 60 * MB);
  bf16*  ob  = (bf16*)(ws + 12 * MB);    // attn out, reuses xs
  float* xt  = (float*)(ws + 28 * MB);   // residual fp32, reuses q+k
  bf16*  hb  = (bf16*)(ws + 60 * MB);    // LN2 out, reuses vt
  bf16*  a1  = (bf16*)(ws + 12 * MB);    // FFN mid, reuses ob
  float* out = (float*)d_out;

  prep_w<<<1536, 256, 0, stream>>>(wq, wk, wv, wo, w1, w2, wT);
  ln_k<<<8192, 256, 0, stream>>>(x, gx, bx, xs);
  gemm_k<0, 24><<<1536, 256, 0, stream>>>(xs, wT, nullptr, nullptr, nullptr, qb);
  attn_k<<<512, 256, 0, stream>>>(qb, kb, vtb, ob);
  gemm_k<2, 8><<<512, 256, 0, stream>>>(ob, wT + (size_t)3 * MB, bo, x, xt, nullptr);
  ln_k<<<8192, 256, 0, stream>>>(xt, gf, bfp, hb);
  gemm_k<3, 8><<<512, 256, 0, stream>>>(hb, wT + (size_t)4 * MB, b1, nullptr, nullptr, a1);
  gemm_k<2, 8><<<512, 256, 0, stream>>>(a1, wT + (size_t)5 * MB, b2, xt, out, nullptr);
}

// Round 13
// 264.067 us; speedup vs baseline: 2.5609x; 1.0277x over previous
//
#include <hip/hip_runtime.h>
#include <hip/hip_bf16.h>

typedef __bf16 bf16;
typedef bf16 bf16x8 __attribute__((ext_vector_type(8)));
typedef bf16 bf16x4 __attribute__((ext_vector_type(4)));
typedef float f32x4 __attribute__((ext_vector_type(4)));
typedef float f32x16 __attribute__((ext_vector_type(16)));

#define AS1 __attribute__((address_space(1)))
#define AS3 __attribute__((address_space(3)))

static constexpr int SEQ = 2048;
static constexpr int NH  = 16;
static constexpr int DH  = 64;
static constexpr float SCLQ = 0.125f * 1.44269504088896340736f; // 1/sqrt(64)*log2(e)

__device__ __forceinline__ void gload16(const void* g, void* l) {
  __builtin_amdgcn_global_load_lds((const AS1 void*)g, (AS3 void*)l, 16, 0, 0);
}

__device__ __forceinline__ unsigned pk2(float a, float b) {
  union { bf16 h[2]; unsigned u; } z;
  z.h[0] = (bf16)a; z.h[1] = (bf16)b;
  return z.u;
}

// v_permlane32_swap_b32: a.upper32lanes <-> b.lower32lanes
__device__ __forceinline__ void plswap(unsigned &a, unsigned &b) {
  asm volatile("v_permlane32_swap_b32 %0, %1" : "+v"(a), "+v"(b));
}

#define MFMA32(d, a, b) d = __builtin_amdgcn_mfma_f32_32x32x16_bf16(a, b, d, 0, 0, 0)

// ---------- fused: LN1 (blocks 0..8191) + weight transpose (blocks 8192..9727) ----------
__global__ __launch_bounds__(256) void prep_ln(
    const float* __restrict__ w0, const float* __restrict__ w1,
    const float* __restrict__ w2, const float* __restrict__ w3,
    const float* __restrict__ w4, const float* __restrict__ w5,
    bf16* __restrict__ dst,
    const float* __restrict__ x, const float* __restrict__ g,
    const float* __restrict__ bb, bf16* __restrict__ xs)
{
  __shared__ float tile[64][65];
  __shared__ float red[8];
  int bid = blockIdx.x;
  int t = threadIdx.x;

  if (bid < 8192) {                     // ---- LayerNorm 1: x (f32) -> xs (bf16)
    int row = bid;
    float4 v = ((const float4*)(x + (size_t)row * 1024))[t];
    float s  = v.x + v.y + v.z + v.w;
    float s2 = v.x * v.x + v.y * v.y + v.z * v.z + v.w * v.w;
    #pragma unroll
    for (int m = 1; m < 64; m <<= 1) { s += __shfl_xor(s, m); s2 += __shfl_xor(s2, m); }
    int w = t >> 6;
    if ((t & 63) == 0) { red[w] = s; red[4 + w] = s2; }
    __syncthreads();
    s  = red[0] + red[1] + red[2] + red[3];
    s2 = red[4] + red[5] + red[6] + red[7];
    float mu  = s * (1.0f / 1024.0f);
    float var = s2 * (1.0f / 1024.0f) - mu * mu;
    float rst = rsqrtf(var + 1e-5f);
    float4 gv = ((const float4*)g)[t];
    float4 bv = ((const float4*)bb)[t];
    bf16x4 o;
    o[0] = (bf16)((v.x - mu) * rst * gv.x + bv.x);
    o[1] = (bf16)((v.y - mu) * rst * gv.y + bv.y);
    o[2] = (bf16)((v.z - mu) * rst * gv.z + bv.z);
    o[3] = (bf16)((v.w - mu) * rst * gv.w + bv.w);
    *(bf16x4*)(xs + (size_t)row * 1024 + t * 4) = o;
    return;
  }

  // ---- weight transpose + fp32->bf16 : Wt[n][k] = W[k][n]
  int pb = bid - 8192;                  // 0..1535
  int wi = pb >> 8;
  int tl = pb & 255;
  int tk = (tl >> 4) << 6;
  int tn = (tl & 15) << 6;
  const float* W = w0;
  if (wi == 1) W = w1; else if (wi == 2) W = w2; else if (wi == 3) W = w3;
  else if (wi == 4) W = w4; else if (wi == 5) W = w5;
  #pragma unroll
  for (int rep = 0; rep < 16; ++rep) {
    int idx = rep * 256 + t;
    int i = idx >> 6, j = idx & 63;
    tile[i][j] = W[(size_t)(tk + i) * 1024 + tn + j];
  }
  __syncthreads();
  bf16* out = dst + (size_t)wi * 1024 * 1024;
  #pragma unroll
  for (int rep = 0; rep < 16; ++rep) {
    int idx = rep * 256 + t;
    int i = idx >> 6, j = idx & 63;
    out[(size_t)(tn + i) * 1024 + tk + j] = (bf16)tile[j][i];
  }
}

// ---------- LayerNorm: f32 (BF=0) or bf16 (BF=1) in -> bf16 out ----------
template<int BF>
__global__ __launch_bounds__(256) void ln_k(
    const void* __restrict__ xin, const float* __restrict__ g,
    const float* __restrict__ bb, bf16* __restrict__ out)
{
  int row = blockIdx.x;
  int t = threadIdx.x;
  float4 v;
  if constexpr (BF) {
    bf16x4 h = ((const bf16x4*)((const bf16*)xin + (size_t)row * 1024))[t];
    v.x = (float)h[0]; v.y = (float)h[1]; v.z = (float)h[2]; v.w = (float)h[3];
  } else {
    v = ((const float4*)((const float*)xin + (size_t)row * 1024))[t];
  }
  float s  = v.x + v.y + v.z + v.w;
  float s2 = v.x * v.x + v.y * v.y + v.z * v.z + v.w * v.w;
  #pragma unroll
  for (int m = 1; m < 64; m <<= 1) { s += __shfl_xor(s, m); s2 += __shfl_xor(s2, m); }
  __shared__ float red[8];
  int w = t >> 6;
  if ((t & 63) == 0) { red[w] = s; red[4 + w] = s2; }
  __syncthreads();
  s  = red[0] + red[1] + red[2] + red[3];
  s2 = red[4] + red[5] + red[6] + red[7];
  float mu  = s * (1.0f / 1024.0f);
  float var = s2 * (1.0f / 1024.0f) - mu * mu;
  float rst = rsqrtf(var + 1e-5f);
  float4 gv = ((const float4*)g)[t];
  float4 bv = ((const float4*)bb)[t];
  bf16x4 o;
  o[0] = (bf16)((v.x - mu) * rst * gv.x + bv.x);
  o[1] = (bf16)((v.y - mu) * rst * gv.y + bv.y);
  o[2] = (bf16)((v.z - mu) * rst * gv.z + bv.z);
  o[3] = (bf16)((v.w - mu) * rst * gv.w + bv.w);
  *(bf16x4*)(out + (size_t)row * 1024 + t * 4) = o;
}

// ---------- GEMM: C[M=8192][N=NT*128] = A[M][1024] * Bt[N][1024]^T ----------
// m97 structure (round-3 verified): 128x128 tile, BK=64, 4 waves.
// EPI 0: fused QKV -> q (pre-scaled by SCLQ) / k (B,H,S,Dh) + v^T (B,H,Dh,S)
// EPI 2: out bf16 = acc + bias[col] + resf[row][col]   (O-proj -> xt bf16)
// EPI 3: out bf16 = relu(acc + bias[col])              (FFN1)
// EPI 4: out fp32 = acc + bias[col] + (f32)resb[..]    (FFN2 -> d_out)
template<int EPI, int NT>
__global__ __launch_bounds__(256) void gemm_k(
    const bf16* __restrict__ A, const bf16* __restrict__ Bt,
    const float* __restrict__ bias, const float* __restrict__ resf,
    const bf16* __restrict__ resb,
    float* __restrict__ outf, bf16* __restrict__ outb)
{
  __shared__ bf16 lA[128 * 64];
  __shared__ bf16 lB[128 * 64];
  int t = threadIdx.x;
  int wg = blockIdx.x;
  int swz = (wg & 7) * (NT * 8) + (wg >> 3);   // XCD-bijective swizzle
  int mt = swz / NT, nt = swz % NT;
  int lane = t & 63, w = t >> 6;
  int l16 = lane & 15, lh = lane >> 4;
  int wr = w >> 1, wc = w & 1;

  f32x4 acc[4][4] = {};
  const size_t mbase = (size_t)mt * 128;
  const size_t nbase = (size_t)nt * 128;
  int u = t & 7;

  for (int ks = 0; ks < 16; ++ks) {
    int k0 = ks * 64;
    #pragma unroll
    for (int i = 0; i < 4; ++i) {
      int row = i * 32 + (t >> 3);
      int up = u ^ (row & 7);
      gload16(A  + (mbase + row) * 1024 + k0 + up * 8, lA + i * 2048 + w * 512);
      gload16(Bt + (nbase + row) * 1024 + k0 + up * 8, lB + i * 2048 + w * 512);
    }
    __syncthreads();
    #pragma unroll
    for (int kc = 0; kc < 2; ++kc) {
      bf16x8 af[4], bfr[4];
      #pragma unroll
      for (int mi = 0; mi < 4; ++mi) {
        int row = wr * 64 + mi * 16 + l16;
        af[mi] = *(const bf16x8*)(lA + row * 64 + (((kc * 4 + lh) ^ (row & 7)) * 8));
      }
      #pragma unroll
      for (int ni = 0; ni < 4; ++ni) {
        int row = wc * 64 + ni * 16 + l16;
        bfr[ni] = *(const bf16x8*)(lB + row * 64 + (((kc * 4 + lh) ^ (row & 7)) * 8));
      }
      #pragma unroll
      for (int mi = 0; mi < 4; ++mi)
        #pragma unroll
        for (int ni = 0; ni < 4; ++ni)
          acc[mi][ni] = __builtin_amdgcn_mfma_f32_16x16x32_bf16(af[mi], bfr[ni], acc[mi][ni], 0, 0, 0);
    }
    __syncthreads();
  }

  int mrow0 = mt * 128 + wr * 64;
  int ncol0 = nt * 128 + wc * 64;
  #pragma unroll
  for (int mi = 0; mi < 4; ++mi) {
    #pragma unroll
    for (int ni = 0; ni < 4; ++ni) {
      if constexpr (EPI == 0) {
        int gcol = ncol0 + ni * 16 + l16;
        int which = gcol >> 10;                  // 0=q 1=k 2=v
        int col = gcol & 1023;
        int h = col >> 6, dh = col & 63;
        bf16* dst = outb + (size_t)which * (size_t)(4 * NH * SEQ * DH);
        if (which == 2) {
          // V^T: 4 consecutive s per lane -> one 8B store
          int s0 = mrow0 + mi * 16 + lh * 4;
          int b = s0 >> 11, s = s0 & 2047;
          bf16x4 pkv;
          #pragma unroll
          for (int r = 0; r < 4; ++r) pkv[r] = (bf16)acc[mi][ni][r];
          *(bf16x4*)(dst + (((size_t)((b * NH + h) * DH + dh)) << 11) + s) = pkv;
        } else {
          #pragma unroll
          for (int r = 0; r < 4; ++r) {
            int grow = mrow0 + mi * 16 + lh * 4 + r;
            int b = grow >> 11, s = grow & 2047;
            float v = acc[mi][ni][r];
            if (which == 0) v *= SCLQ;           // fold softmax scale into q
            dst[(((size_t)((b * NH + h) * SEQ + s)) << 6) + dh] = (bf16)v;
          }
        }
      } else {
        #pragma unroll
        for (int r = 0; r < 4; ++r) {
          int grow = mrow0 + mi * 16 + lh * 4 + r;
          int gcol = ncol0 + ni * 16 + l16;
          float v = acc[mi][ni][r];
          size_t idx = (size_t)grow * 1024 + gcol;
          if constexpr (EPI == 2) {
            outb[idx] = (bf16)(v + bias[gcol] + resf[idx]);
          } else if constexpr (EPI == 3) {
            float z = v + bias[gcol];
            outb[idx] = (bf16)(z > 0.f ? z : 0.f);
          } else {                               // EPI == 4
            outf[idx] = v + bias[gcol] + (float)resb[idx];
          }
        }
      }
    }
  }
}

// ---------- flash attention, swapped-QK 32x32, 2 q-tiles per wave ----------
// Session-best configuration (round 5): 512 blocks x 4 waves, 64 q-rows/wave,
// double-buffered K/V via global_load_lds, static m=0 softmax (q pre-scaled),
// pk2+permlane32_swap P-redistribution, 4 independent MFMA chains per wave.
__global__ __launch_bounds__(256, 2) void attn_k(
    const bf16* __restrict__ q, const bf16* __restrict__ kk,
    const bf16* __restrict__ vt, bf16* __restrict__ o)
{
  __shared__ bf16 lK[2][4096];   // [key 0..63][dh 0..63], unit-swizzled
  __shared__ bf16 lV[2][4096];   // [dh 0..63][key 0..63], unit-swizzled

  int t = threadIdx.x;
  int lane = t & 63, w = t >> 6;
  int l31 = lane & 31, hi = lane >> 5;
  int bid = blockIdx.x;
  int swz = (bid & 7) * 64 + (bid >> 3);   // 8 bh per XCD, all q-tiles local
  int bh = swz >> 3, qt = swz & 7;
  int q0 = qt * 256 + w * 64;
  size_t bhS = (size_t)bh * SEQ;

  // Q fragments (B-operand): lane holds q = base+l31, dh = ks*16 + hi*8 + j
  const bf16* qrow0 = q + (bhS + q0 + l31) * 64 + hi * 8;
  const bf16* qrow1 = qrow0 + 32 * 64;
  bf16x8 aq0[4], aq1[4];
  #pragma unroll
  for (int ks = 0; ks < 4; ++ks) {
    aq0[ks] = *(const bf16x8*)(qrow0 + ks * 16);
    aq1[ks] = *(const bf16x8*)(qrow1 + ks * 16);
  }

  // staging source addresses (per-lane, pre-swizzled on the 16B unit)
  int srow = t >> 3;
  int u8 = (t & 7) ^ (srow & 7);
  const bf16* kSrc = kk + (bhS + srow) * 64 + u8 * 8;
  const bf16* vSrc = vt + ((size_t)bh * 64 + srow) * SEQ + u8 * 8;

  f32x16 oa00 = {}, oa01 = {}, oa10 = {}, oa11 = {};
  float lsum0 = 0.f, lsum1 = 0.f;

  // prologue: stage tile 0 into buffer 0
  gload16(kSrc,            &lK[0][w * 512]);
  gload16(kSrc + 2048,     &lK[0][2048 + w * 512]);
  gload16(vSrc,            &lV[0][w * 512]);
  gload16(vSrc + 32 * SEQ, &lV[0][2048 + w * 512]);
  __syncthreads();

  #pragma unroll 2
  for (int kt = 0; kt < 32; ++kt) {
    const int cur = kt & 1;
    // prefetch next tile into the other buffer (issue before compute)
    if (kt < 31) {
      const bf16* ks2 = kSrc + (size_t)(kt + 1) * 4096;
      const bf16* vs2 = vSrc + (kt + 1) * 64;
      gload16(ks2,            &lK[cur ^ 1][w * 512]);
      gload16(ks2 + 2048,     &lK[cur ^ 1][2048 + w * 512]);
      gload16(vs2,            &lV[cur ^ 1][w * 512]);
      gload16(vs2 + 32 * SEQ, &lV[cur ^ 1][2048 + w * 512]);
    }

    const bf16* bK = &lK[cur][0];
    const bf16* bV = &lV[cur][0];

    // QK^T (swapped): 4 independent accumulator chains
    f32x16 sA0 = {}, sB0 = {}, sA1 = {}, sB1 = {};
    __builtin_amdgcn_s_setprio(1);
    #pragma unroll
    for (int ks = 0; ks < 4; ++ks) {
      int u = ((2 * ks + hi) ^ (l31 & 7)) * 8;
      bf16x8 k0 = *(const bf16x8*)(bK + l31 * 64 + u);
      bf16x8 k1 = *(const bf16x8*)(bK + (32 + l31) * 64 + u);
      MFMA32(sA0, k0, aq0[ks]);
      MFMA32(sA1, k0, aq1[ks]);
      MFMA32(sB0, k1, aq0[ks]);
      MFMA32(sB1, k1, aq1[ks]);
    }
    __builtin_amdgcn_s_setprio(0);

    // softmax (static m=0) + pack/swap into PV A-fragments, per q-tile
    unsigned cv0[4][4], cv1[4][4];
    {
      float p[32];
      #pragma unroll
      for (int i = 0; i < 16; ++i) {
        p[i]      = __builtin_amdgcn_exp2f(sA0[i]);
        p[16 + i] = __builtin_amdgcn_exp2f(sB0[i]);
      }
      float t8[8];
      #pragma unroll
      for (int i = 0; i < 8; ++i)
        t8[i] = (p[4 * i] + p[4 * i + 1]) + (p[4 * i + 2] + p[4 * i + 3]);
      lsum0 += ((t8[0] + t8[1]) + (t8[2] + t8[3])) + ((t8[4] + t8[5]) + (t8[6] + t8[7]));
      #pragma unroll
      for (int ks = 0; ks < 4; ++ks) {
        int g = 8 * ks;
        unsigned X0 = pk2(p[g],     p[g + 1]), X1 = pk2(p[g + 2], p[g + 3]);
        unsigned Y0 = pk2(p[g + 4], p[g + 5]), Y1 = pk2(p[g + 6], p[g + 7]);
        plswap(X0, Y0);
        plswap(X1, Y1);
        cv0[ks][0] = X0; cv0[ks][1] = X1; cv0[ks][2] = Y0; cv0[ks][3] = Y1;
      }
    }
    {
      float p[32];
      #pragma unroll
      for (int i = 0; i < 16; ++i) {
        p[i]      = __builtin_amdgcn_exp2f(sA1[i]);
        p[16 + i] = __builtin_amdgcn_exp2f(sB1[i]);
      }
      float t8[8];
      #pragma unroll
      for (int i = 0; i < 8; ++i)
        t8[i] = (p[4 * i] + p[4 * i + 1]) + (p[4 * i + 2] + p[4 * i + 3]);
      lsum1 += ((t8[0] + t8[1]) + (t8[2] + t8[3])) + ((t8[4] + t8[5]) + (t8[6] + t8[7]));
      #pragma unroll
      for (int ks = 0; ks < 4; ++ks) {
        int g = 8 * ks;
        unsigned X0 = pk2(p[g],     p[g + 1]), X1 = pk2(p[g + 2], p[g + 3]);
        unsigned Y0 = pk2(p[g + 4], p[g + 5]), Y1 = pk2(p[g + 6], p[g + 7]);
        plswap(X0, Y0);
        plswap(X1, Y1);
        cv1[ks][0] = X0; cv1[ks][1] = X1; cv1[ks][2] = Y0; cv1[ks][3] = Y1;
      }
    }

    // PV: 4 independent chains, shared V fragments
    __builtin_amdgcn_s_setprio(1);
    #pragma unroll
    for (int ks = 0; ks < 4; ++ks) {
      int u = ((2 * ks + hi) ^ (l31 & 7)) * 8;
      bf16x8 v0 = *(const bf16x8*)(bV + l31 * 64 + u);
      bf16x8 v1 = *(const bf16x8*)(bV + (32 + l31) * 64 + u);
      union { unsigned u4[4]; bf16x8 v; } a0, a1;
      a0.u4[0] = cv0[ks][0]; a0.u4[1] = cv0[ks][1]; a0.u4[2] = cv0[ks][2]; a0.u4[3] = cv0[ks][3];
      a1.u4[0] = cv1[ks][0]; a1.u4[1] = cv1[ks][1]; a1.u4[2] = cv1[ks][2]; a1.u4[3] = cv1[ks][3];
      MFMA32(oa00, a0.v, v0);
      MFMA32(oa01, a0.v, v1);
      MFMA32(oa10, a1.v, v0);
      MFMA32(oa11, a1.v, v1);
    }
    __builtin_amdgcn_s_setprio(0);

    __syncthreads();  // drains vmcnt (prefetch landed) + lgkm; flips buffer
  }

  // epilogue: combine halves of l, broadcast 1/l to O rows, store
  lsum0 += __shfl_xor(lsum0, 32);
  lsum1 += __shfl_xor(lsum1, 32);
  float inv0 = 1.0f / lsum0;                  // valid for q-row = l31 (tile 0)
  float inv1 = 1.0f / lsum1;                  // tile 1
  int bb = bh >> 4, hh = bh & 15;
  size_t obase = ((size_t)bb * SEQ + q0) * 1024 + (size_t)hh * 64;
  #pragma unroll
  for (int r = 0; r < 16; ++r) {
    int qrw = (r & 3) + 8 * (r >> 2) + 4 * hi;    // C/D row within 32
    float iv0 = __shfl(inv0, qrw);
    float iv1 = __shfl(inv1, qrw);
    size_t b0 = obase + (size_t)qrw * 1024;
    size_t b1 = obase + (size_t)(32 + qrw) * 1024;
    o[b0 + l31]      = (bf16)(oa00[r] * iv0);
    o[b0 + 32 + l31] = (bf16)(oa01[r] * iv0);
    o[b1 + l31]      = (bf16)(oa10[r] * iv1);
    o[b1 + 32 + l31] = (bf16)(oa11[r] * iv1);
  }
}

extern "C" void kernel_launch(void* const* d_in, const int* in_sizes, int n_in,
                              void* d_out, int out_size, void* d_ws, size_t ws_size,
                              hipStream_t stream) {
  const float* x   = (const float*)d_in[0];
  const float* wq  = (const float*)d_in[1];
  const float* wk  = (const float*)d_in[2];
  const float* wv  = (const float*)d_in[3];
  const float* wo  = (const float*)d_in[4];
  const float* bo  = (const float*)d_in[5];
  const float* gx  = (const float*)d_in[6];
  const float* bx  = (const float*)d_in[7];
  const float* gf  = (const float*)d_in[8];
  const float* bfp = (const float*)d_in[9];
  const float* w1  = (const float*)d_in[10];
  const float* b1  = (const float*)d_in[11];
  const float* w2  = (const float*)d_in[12];
  const float* b2  = (const float*)d_in[13];

  char* ws = (char*)d_ws;
  const size_t MB = 1024 * 1024;
  bf16*  wT  = (bf16*)ws;                // 6 x 2MB bf16 transposed weights
  bf16*  xs  = (bf16*)(ws + 12 * MB);    // LN1 out          (dead after QKV)
  bf16*  qb  = (bf16*)(ws + 28 * MB);    // q,k,vt contiguous (dead after attn)
  bf16*  kb  = (bf16*)(ws + 44 * MB);
  bf16*  vtb = (bf16*)(ws + 60 * MB);
  bf16*  ob  = (bf16*)(ws + 12 * MB);    // attn out, reuses xs
  bf16*  xtb = (bf16*)(ws + 28 * MB);    // residual xt as bf16, reuses q
  bf16*  hb  = (bf16*)(ws + 60 * MB);    // LN2 out, reuses vt
  bf16*  a1  = (bf16*)(ws + 12 * MB);    // FFN mid, reuses ob
  float* out = (float*)d_out;

  prep_ln<<<9728, 256, 0, stream>>>(wq, wk, wv, wo, w1, w2, wT, x, gx, bx, xs);
  gemm_k<0, 24><<<1536, 256, 0, stream>>>(xs, wT, nullptr, nullptr, nullptr, nullptr, qb);
  attn_k<<<512, 256, 0, stream>>>(qb, kb, vtb, ob);
  gemm_k<2, 8><<<512, 256, 0, stream>>>(ob, wT + (size_t)3 * MB, bo, x, nullptr, nullptr, xtb);
  ln_k<1><<<8192, 256, 0, stream>>>(xtb, gf, bfp, hb);
  gemm_k<3, 8><<<512, 256, 0, stream>>>(hb, wT + (size_t)4 * MB, b1, nullptr, nullptr, nullptr, a1);
  gemm_k<4, 8><<<512, 256, 0, stream>>>(a1, wT + (size_t)5 * MB, b2, nullptr, xtb, out, nullptr);
}

// Round 14
// 263.292 us; speedup vs baseline: 2.5685x; 1.0029x over previous
//
#include <hip/hip_runtime.h>
#include <hip/hip_bf16.h>

typedef __bf16 bf16;
typedef bf16 bf16x8 __attribute__((ext_vector_type(8)));
typedef bf16 bf16x4 __attribute__((ext_vector_type(4)));
typedef float f32x4 __attribute__((ext_vector_type(4)));
typedef float f32x16 __attribute__((ext_vector_type(16)));

#define AS1 __attribute__((address_space(1)))
#define AS3 __attribute__((address_space(3)))

static constexpr int SEQ = 2048;
static constexpr int NH  = 16;
static constexpr int DH  = 64;
static constexpr float SCLQ = 0.125f * 1.44269504088896340736f; // 1/sqrt(64)*log2(e)

__device__ __forceinline__ void gload16(const void* g, void* l) {
  __builtin_amdgcn_global_load_lds((const AS1 void*)g, (AS3 void*)l, 16, 0, 0);
}

__device__ __forceinline__ unsigned pk2(float a, float b) {
  union { bf16 h[2]; unsigned u; } z;
  z.h[0] = (bf16)a; z.h[1] = (bf16)b;
  return z.u;
}

// v_permlane32_swap_b32: a.upper32lanes <-> b.lower32lanes
__device__ __forceinline__ void plswap(unsigned &a, unsigned &b) {
  asm volatile("v_permlane32_swap_b32 %0, %1" : "+v"(a), "+v"(b));
}

#define MFMA32(d, a, b) d = __builtin_amdgcn_mfma_f32_32x32x16_bf16(a, b, d, 0, 0, 0)

// ---------- fused: LN1 (blocks 0..8191) + weight transpose (blocks 8192..9727) ----------
__global__ __launch_bounds__(256) void prep_ln(
    const float* __restrict__ w0, const float* __restrict__ w1,
    const float* __restrict__ w2, const float* __restrict__ w3,
    const float* __restrict__ w4, const float* __restrict__ w5,
    bf16* __restrict__ dst,
    const float* __restrict__ x, const float* __restrict__ g,
    const float* __restrict__ bb, bf16* __restrict__ xs)
{
  __shared__ float tile[64][65];
  __shared__ float red[8];
  int bid = blockIdx.x;
  int t = threadIdx.x;

  if (bid < 8192) {                     // ---- LayerNorm 1: x (f32) -> xs (bf16)
    int row = bid;
    float4 v = ((const float4*)(x + (size_t)row * 1024))[t];
    float s  = v.x + v.y + v.z + v.w;
    float s2 = v.x * v.x + v.y * v.y + v.z * v.z + v.w * v.w;
    #pragma unroll
    for (int m = 1; m < 64; m <<= 1) { s += __shfl_xor(s, m); s2 += __shfl_xor(s2, m); }
    int w = t >> 6;
    if ((t & 63) == 0) { red[w] = s; red[4 + w] = s2; }
    __syncthreads();
    s  = red[0] + red[1] + red[2] + red[3];
    s2 = red[4] + red[5] + red[6] + red[7];
    float mu  = s * (1.0f / 1024.0f);
    float var = s2 * (1.0f / 1024.0f) - mu * mu;
    float rst = rsqrtf(var + 1e-5f);
    float4 gv = ((const float4*)g)[t];
    float4 bv = ((const float4*)bb)[t];
    bf16x4 o;
    o[0] = (bf16)((v.x - mu) * rst * gv.x + bv.x);
    o[1] = (bf16)((v.y - mu) * rst * gv.y + bv.y);
    o[2] = (bf16)((v.z - mu) * rst * gv.z + bv.z);
    o[3] = (bf16)((v.w - mu) * rst * gv.w + bv.w);
    *(bf16x4*)(xs + (size_t)row * 1024 + t * 4) = o;
    return;
  }

  // ---- weight transpose + fp32->bf16 : Wt[n][k] = W[k][n]
  int pb = bid - 8192;                  // 0..1535
  int wi = pb >> 8;
  int tl = pb & 255;
  int tk = (tl >> 4) << 6;
  int tn = (tl & 15) << 6;
  const float* W = w0;
  if (wi == 1) W = w1; else if (wi == 2) W = w2; else if (wi == 3) W = w3;
  else if (wi == 4) W = w4; else if (wi == 5) W = w5;
  #pragma unroll
  for (int rep = 0; rep < 16; ++rep) {
    int idx = rep * 256 + t;
    int i = idx >> 6, j = idx & 63;
    tile[i][j] = W[(size_t)(tk + i) * 1024 + tn + j];
  }
  __syncthreads();
  bf16* out = dst + (size_t)wi * 1024 * 1024;
  #pragma unroll
  for (int rep = 0; rep < 16; ++rep) {
    int idx = rep * 256 + t;
    int i = idx >> 6, j = idx & 63;
    out[(size_t)(tn + i) * 1024 + tk + j] = (bf16)tile[j][i];
  }
}

// ---------- LayerNorm: f32 (BF=0) or bf16 (BF=1) in -> bf16 out ----------
template<int BF>
__global__ __launch_bounds__(256) void ln_k(
    const void* __restrict__ xin, const float* __restrict__ g,
    const float* __restrict__ bb, bf16* __restrict__ out)
{
  int row = blockIdx.x;
  int t = threadIdx.x;
  float4 v;
  if constexpr (BF) {
    bf16x4 h = ((const bf16x4*)((const bf16*)xin + (size_t)row * 1024))[t];
    v.x = (float)h[0]; v.y = (float)h[1]; v.z = (float)h[2]; v.w = (float)h[3];
  } else {
    v = ((const float4*)((const float*)xin + (size_t)row * 1024))[t];
  }
  float s  = v.x + v.y + v.z + v.w;
  float s2 = v.x * v.x + v.y * v.y + v.z * v.z + v.w * v.w;
  #pragma unroll
  for (int m = 1; m < 64; m <<= 1) { s += __shfl_xor(s, m); s2 += __shfl_xor(s2, m); }
  __shared__ float red[8];
  int w = t >> 6;
  if ((t & 63) == 0) { red[w] = s; red[4 + w] = s2; }
  __syncthreads();
  s  = red[0] + red[1] + red[2] + red[3];
  s2 = red[4] + red[5] + red[6] + red[7];
  float mu  = s * (1.0f / 1024.0f);
  float var = s2 * (1.0f / 1024.0f) - mu * mu;
  float rst = rsqrtf(var + 1e-5f);
  float4 gv = ((const float4*)g)[t];
  float4 bv = ((const float4*)bb)[t];
  bf16x4 o;
  o[0] = (bf16)((v.x - mu) * rst * gv.x + bv.x);
  o[1] = (bf16)((v.y - mu) * rst * gv.y + bv.y);
  o[2] = (bf16)((v.z - mu) * rst * gv.z + bv.z);
  o[3] = (bf16)((v.w - mu) * rst * gv.w + bv.w);
  *(bf16x4*)(out + (size_t)row * 1024 + t * 4) = o;
}

// ---------- GEMM: C[M=8192][N=NT*128] = A[M][1024] * Bt[N][1024]^T ----------
// m97 structure (round-3 verified): 128x128 tile, BK=64, 4 waves.
// EPI 0: fused QKV -> q (pre-scaled by SCLQ) / k (B,H,S,Dh) + v^T (B,H,Dh,S)
// EPI 2: out bf16 = acc + bias[col] + resf[row][col]   (O-proj -> xt bf16)
// EPI 3: out bf16 = relu(acc + bias[col])              (FFN1)
// EPI 4: out fp32 = acc + bias[col] + (f32)resb[..]    (FFN2 -> d_out)
template<int EPI, int NT>
__global__ __launch_bounds__(256) void gemm_k(
    const bf16* __restrict__ A, const bf16* __restrict__ Bt,
    const float* __restrict__ bias, const float* __restrict__ resf,
    const bf16* __restrict__ resb,
    float* __restrict__ outf, bf16* __restrict__ outb)
{
  __shared__ bf16 lA[128 * 64];
  __shared__ bf16 lB[128 * 64];
  int t = threadIdx.x;
  int wg = blockIdx.x;
  int swz = (wg & 7) * (NT * 8) + (wg >> 3);   // XCD-bijective swizzle
  int mt = swz / NT, nt = swz % NT;
  int lane = t & 63, w = t >> 6;
  int l16 = lane & 15, lh = lane >> 4;
  int wr = w >> 1, wc = w & 1;

  f32x4 acc[4][4] = {};
  const size_t mbase = (size_t)mt * 128;
  const size_t nbase = (size_t)nt * 128;
  int u = t & 7;

  for (int ks = 0; ks < 16; ++ks) {
    int k0 = ks * 64;
    #pragma unroll
    for (int i = 0; i < 4; ++i) {
      int row = i * 32 + (t >> 3);
      int up = u ^ (row & 7);
      gload16(A  + (mbase + row) * 1024 + k0 + up * 8, lA + i * 2048 + w * 512);
      gload16(Bt + (nbase + row) * 1024 + k0 + up * 8, lB + i * 2048 + w * 512);
    }
    __syncthreads();
    #pragma unroll
    for (int kc = 0; kc < 2; ++kc) {
      bf16x8 af[4], bfr[4];
      #pragma unroll
      for (int mi = 0; mi < 4; ++mi) {
        int row = wr * 64 + mi * 16 + l16;
        af[mi] = *(const bf16x8*)(lA + row * 64 + (((kc * 4 + lh) ^ (row & 7)) * 8));
      }
      #pragma unroll
      for (int ni = 0; ni < 4; ++ni) {
        int row = wc * 64 + ni * 16 + l16;
        bfr[ni] = *(const bf16x8*)(lB + row * 64 + (((kc * 4 + lh) ^ (row & 7)) * 8));
      }
      #pragma unroll
      for (int mi = 0; mi < 4; ++mi)
        #pragma unroll
        for (int ni = 0; ni < 4; ++ni)
          acc[mi][ni] = __builtin_amdgcn_mfma_f32_16x16x32_bf16(af[mi], bfr[ni], acc[mi][ni], 0, 0, 0);
    }
    __syncthreads();
  }

  int mrow0 = mt * 128 + wr * 64;
  int ncol0 = nt * 128 + wc * 64;
  #pragma unroll
  for (int mi = 0; mi < 4; ++mi) {
    #pragma unroll
    for (int ni = 0; ni < 4; ++ni) {
      if constexpr (EPI == 0) {
        int gcol = ncol0 + ni * 16 + l16;
        int which = gcol >> 10;                  // 0=q 1=k 2=v
        int col = gcol & 1023;
        int h = col >> 6, dh = col & 63;
        bf16* dst = outb + (size_t)which * (size_t)(4 * NH * SEQ * DH);
        if (which == 2) {
          // V^T: 4 consecutive s per lane -> one 8B store
          int s0 = mrow0 + mi * 16 + lh * 4;
          int b = s0 >> 11, s = s0 & 2047;
          bf16x4 pkv;
          #pragma unroll
          for (int r = 0; r < 4; ++r) pkv[r] = (bf16)acc[mi][ni][r];
          *(bf16x4*)(dst + (((size_t)((b * NH + h) * DH + dh)) << 11) + s) = pkv;
        } else {
          #pragma unroll
          for (int r = 0; r < 4; ++r) {
            int grow = mrow0 + mi * 16 + lh * 4 + r;
            int b = grow >> 11, s = grow & 2047;
            float v = acc[mi][ni][r];
            if (which == 0) v *= SCLQ;           // fold softmax scale into q
            dst[(((size_t)((b * NH + h) * SEQ + s)) << 6) + dh] = (bf16)v;
          }
        }
      } else {
        #pragma unroll
        for (int r = 0; r < 4; ++r) {
          int grow = mrow0 + mi * 16 + lh * 4 + r;
          int gcol = ncol0 + ni * 16 + l16;
          float v = acc[mi][ni][r];
          size_t idx = (size_t)grow * 1024 + gcol;
          if constexpr (EPI == 2) {
            outb[idx] = (bf16)(v + bias[gcol] + resf[idx]);
          } else if constexpr (EPI == 3) {
            float z = v + bias[gcol];
            outb[idx] = (bf16)(z > 0.f ? z : 0.f);
          } else {                               // EPI == 4
            outf[idx] = v + bias[gcol] + (float)resb[idx];
          }
        }
      }
    }
  }
}

// ---------- flash attention, swapped-QK 32x32, 2 q-tiles per wave ----------
// Round-5 core + FZ-hoist: QK chains start as mfma(k, aq[0], FZ) with one
// hoisted zero vector, removing 64 per-tile accumulator zero-writes per wave.
__global__ __launch_bounds__(256, 2) void attn_k(
    const bf16* __restrict__ q, const bf16* __restrict__ kk,
    const bf16* __restrict__ vt, bf16* __restrict__ o)
{
  __shared__ bf16 lK[2][4096];   // [key 0..63][dh 0..63], unit-swizzled
  __shared__ bf16 lV[2][4096];   // [dh 0..63][key 0..63], unit-swizzled

  int t = threadIdx.x;
  int lane = t & 63, w = t >> 6;
  int l31 = lane & 31, hi = lane >> 5;
  int bid = blockIdx.x;
  int swz = (bid & 7) * 64 + (bid >> 3);   // 8 bh per XCD, all q-tiles local
  int bh = swz >> 3, qt = swz & 7;
  int q0 = qt * 256 + w * 64;
  size_t bhS = (size_t)bh * SEQ;

  // Q fragments (B-operand): lane holds q = base+l31, dh = ks*16 + hi*8 + j
  const bf16* qrow0 = q + (bhS + q0 + l31) * 64 + hi * 8;
  const bf16* qrow1 = qrow0 + 32 * 64;
  bf16x8 aq0[4], aq1[4];
  #pragma unroll
  for (int ks = 0; ks < 4; ++ks) {
    aq0[ks] = *(const bf16x8*)(qrow0 + ks * 16);
    aq1[ks] = *(const bf16x8*)(qrow1 + ks * 16);
  }

  // staging source addresses (per-lane, pre-swizzled on the 16B unit)
  int srow = t >> 3;
  int u8 = (t & 7) ^ (srow & 7);
  const bf16* kSrc = kk + (bhS + srow) * 64 + u8 * 8;
  const bf16* vSrc = vt + ((size_t)bh * 64 + srow) * SEQ + u8 * 8;

  f32x16 oa00 = {}, oa01 = {}, oa10 = {}, oa11 = {};
  const f32x16 FZ = {};                    // hoisted zero C-operand (16 VGPR, once)
  float lsum0 = 0.f, lsum1 = 0.f;

  // prologue: stage tile 0 into buffer 0
  gload16(kSrc,            &lK[0][w * 512]);
  gload16(kSrc + 2048,     &lK[0][2048 + w * 512]);
  gload16(vSrc,            &lV[0][w * 512]);
  gload16(vSrc + 32 * SEQ, &lV[0][2048 + w * 512]);
  __syncthreads();

  #pragma unroll 2
  for (int kt = 0; kt < 32; ++kt) {
    const int cur = kt & 1;
    // prefetch next tile into the other buffer (issue before compute)
    if (kt < 31) {
      const bf16* ks2 = kSrc + (size_t)(kt + 1) * 4096;
      const bf16* vs2 = vSrc + (kt + 1) * 64;
      gload16(ks2,            &lK[cur ^ 1][w * 512]);
      gload16(ks2 + 2048,     &lK[cur ^ 1][2048 + w * 512]);
      gload16(vs2,            &lV[cur ^ 1][w * 512]);
      gload16(vs2 + 32 * SEQ, &lV[cur ^ 1][2048 + w * 512]);
    }

    const bf16* bK = &lK[cur][0];
    const bf16* bV = &lV[cur][0];

    // QK^T (swapped): 4 independent accumulator chains, FZ-seeded
    f32x16 sA0, sB0, sA1, sB1;
    __builtin_amdgcn_s_setprio(1);
    #pragma unroll
    for (int ks = 0; ks < 4; ++ks) {
      int u = ((2 * ks + hi) ^ (l31 & 7)) * 8;
      bf16x8 k0 = *(const bf16x8*)(bK + l31 * 64 + u);
      bf16x8 k1 = *(const bf16x8*)(bK + (32 + l31) * 64 + u);
      if (ks == 0) {
        sA0 = __builtin_amdgcn_mfma_f32_32x32x16_bf16(k0, aq0[0], FZ, 0, 0, 0);
        sA1 = __builtin_amdgcn_mfma_f32_32x32x16_bf16(k0, aq1[0], FZ, 0, 0, 0);
        sB0 = __builtin_amdgcn_mfma_f32_32x32x16_bf16(k1, aq0[0], FZ, 0, 0, 0);
        sB1 = __builtin_amdgcn_mfma_f32_32x32x16_bf16(k1, aq1[0], FZ, 0, 0, 0);
      } else {
        MFMA32(sA0, k0, aq0[ks]);
        MFMA32(sA1, k0, aq1[ks]);
        MFMA32(sB0, k1, aq0[ks]);
        MFMA32(sB1, k1, aq1[ks]);
      }
    }
    __builtin_amdgcn_s_setprio(0);

    // softmax (static m=0) + pack/swap into PV A-fragments, per q-tile
    unsigned cv0[4][4], cv1[4][4];
    {
      float p[32];
      #pragma unroll
      for (int i = 0; i < 16; ++i) {
        p[i]      = __builtin_amdgcn_exp2f(sA0[i]);
        p[16 + i] = __builtin_amdgcn_exp2f(sB0[i]);
      }
      float t8[8];
      #pragma unroll
      for (int i = 0; i < 8; ++i)
        t8[i] = (p[4 * i] + p[4 * i + 1]) + (p[4 * i + 2] + p[4 * i + 3]);
      lsum0 += ((t8[0] + t8[1]) + (t8[2] + t8[3])) + ((t8[4] + t8[5]) + (t8[6] + t8[7]));
      #pragma unroll
      for (int ks = 0; ks < 4; ++ks) {
        int g = 8 * ks;
        unsigned X0 = pk2(p[g],     p[g + 1]), X1 = pk2(p[g + 2], p[g + 3]);
        unsigned Y0 = pk2(p[g + 4], p[g + 5]), Y1 = pk2(p[g + 6], p[g + 7]);
        plswap(X0, Y0);
        plswap(X1, Y1);
        cv0[ks][0] = X0; cv0[ks][1] = X1; cv0[ks][2] = Y0; cv0[ks][3] = Y1;
      }
    }
    {
      float p[32];
      #pragma unroll
      for (int i = 0; i < 16; ++i) {
        p[i]      = __builtin_amdgcn_exp2f(sA1[i]);
        p[16 + i] = __builtin_amdgcn_exp2f(sB1[i]);
      }
      float t8[8];
      #pragma unroll
      for (int i = 0; i < 8; ++i)
        t8[i] = (p[4 * i] + p[4 * i + 1]) + (p[4 * i + 2] + p[4 * i + 3]);
      lsum1 += ((t8[0] + t8[1]) + (t8[2] + t8[3])) + ((t8[4] + t8[5]) + (t8[6] + t8[7]));
      #pragma unroll
      for (int ks = 0; ks < 4; ++ks) {
        int g = 8 * ks;
        unsigned X0 = pk2(p[g],     p[g + 1]), X1 = pk2(p[g + 2], p[g + 3]);
        unsigned Y0 = pk2(p[g + 4], p[g + 5]), Y1 = pk2(p[g + 6], p[g + 7]);
        plswap(X0, Y0);
        plswap(X1, Y1);
        cv1[ks][0] = X0; cv1[ks][1] = X1; cv1[ks][2] = Y0; cv1[ks][3] = Y1;
      }
    }

    // PV: 4 independent chains, shared V fragments
    __builtin_amdgcn_s_setprio(1);
    #pragma unroll
    for (int ks = 0; ks < 4; ++ks) {
      int u = ((2 * ks + hi) ^ (l31 & 7)) * 8;
      bf16x8 v0 = *(const bf16x8*)(bV + l31 * 64 + u);
      bf16x8 v1 = *(const bf16x8*)(bV + (32 + l31) * 64 + u);
      union { unsigned u4[4]; bf16x8 v; } a0, a1;
      a0.u4[0] = cv0[ks][0]; a0.u4[1] = cv0[ks][1]; a0.u4[2] = cv0[ks][2]; a0.u4[3] = cv0[ks][3];
      a1.u4[0] = cv1[ks][0]; a1.u4[1] = cv1[ks][1]; a1.u4[2] = cv1[ks][2]; a1.u4[3] = cv1[ks][3];
      MFMA32(oa00, a0.v, v0);
      MFMA32(oa01, a0.v, v1);
      MFMA32(oa10, a1.v, v0);
      MFMA32(oa11, a1.v, v1);
    }
    __builtin_amdgcn_s_setprio(0);

    __syncthreads();  // drains vmcnt (prefetch landed) + lgkm; flips buffer
  }

  // epilogue: combine halves of l, broadcast 1/l to O rows, store
  lsum0 += __shfl_xor(lsum0, 32);
  lsum1 += __shfl_xor(lsum1, 32);
  float inv0 = 1.0f / lsum0;                  // valid for q-row = l31 (tile 0)
  float inv1 = 1.0f / lsum1;                  // tile 1
  int bb = bh >> 4, hh = bh & 15;
  size_t obase = ((size_t)bb * SEQ + q0) * 1024 + (size_t)hh * 64;
  #pragma unroll
  for (int r = 0; r < 16; ++r) {
    int qrw = (r & 3) + 8 * (r >> 2) + 4 * hi;    // C/D row within 32
    float iv0 = __shfl(inv0, qrw);
    float iv1 = __shfl(inv1, qrw);
    size_t b0 = obase + (size_t)qrw * 1024;
    size_t b1 = obase + (size_t)(32 + qrw) * 1024;
    o[b0 + l31]      = (bf16)(oa00[r] * iv0);
    o[b0 + 32 + l31] = (bf16)(oa01[r] * iv0);
    o[b1 + l31]      = (bf16)(oa10[r] * iv1);
    o[b1 + 32 + l31] = (bf16)(oa11[r] * iv1);
  }
}

extern "C" void kernel_launch(void* const* d_in, const int* in_sizes, int n_in,
                              void* d_out, int out_size, void* d_ws, size_t ws_size,
                              hipStream_t stream) {
  const float* x   = (const float*)d_in[0];
  const float* wq  = (const float*)d_in[1];
  const float* wk  = (const float*)d_in[2];
  const float* wv  = (const float*)d_in[3];
  const float* wo  = (const float*)d_in[4];
  const float* bo  = (const float*)d_in[5];
  const float* gx  = (const float*)d_in[6];
  const float* bx  = (const float*)d_in[7];
  const float* gf  = (const float*)d_in[8];
  const float* bfp = (const float*)d_in[9];
  const float* w1  = (const float*)d_in[10];
  const float* b1  = (const float*)d_in[11];
  const float* w2  = (const float*)d_in[12];
  const float* b2  = (const float*)d_in[13];

  char* ws = (char*)d_ws;
  const size_t MB = 1024 * 1024;
  bf16*  wT  = (bf16*)ws;                // 6 x 2MB bf16 transposed weights
  bf16*  xs  = (bf16*)(ws + 12 * MB);    // LN1 out          (dead after QKV)
  bf16*  qb  = (bf16*)(ws + 28 * MB);    // q,k,vt contiguous (dead after attn)
  bf16*  kb  = (bf16*)(ws + 44 * MB);
  bf16*  vtb = (bf16*)(ws + 60 * MB);
  bf16*  ob  = (bf16*)(ws + 12 * MB);    // attn out, reuses xs
  bf16*  xtb = (bf16*)(ws + 28 * MB);    // residual xt as bf16, reuses q
  bf16*  hb  = (bf16*)(ws + 60 * MB);    // LN2 out, reuses vt
  bf16*  a1  = (bf16*)(ws + 12 * MB);    // FFN mid, reuses ob
  float* out = (float*)d_out;

  prep_ln<<<9728, 256, 0, stream>>>(wq, wk, wv, wo, w1, w2, wT, x, gx, bx, xs);
  gemm_k<0, 24><<<1536, 256, 0, stream>>>(xs, wT, nullptr, nullptr, nullptr, nullptr, qb);
  attn_k<<<512, 256, 0, stream>>>(qb, kb, vtb, ob);
  gemm_k<2, 8><<<512, 256, 0, stream>>>(ob, wT + (size_t)3 * MB, bo, x, nullptr, nullptr, xtb);
  ln_k<1><<<8192, 256, 0, stream>>>(xtb, gf, bfp, hb);
  gemm_k<3, 8><<<512, 256, 0, stream>>>(hb, wT + (size_t)4 * MB, b1, nullptr, nullptr, nullptr, a1);
  gemm_k<4, 8><<<512, 256, 0, stream>>>(a1, wT + (size_t)5 * MB, b2, nullptr, xtb, out, nullptr);
}